// Round 1
// baseline (303.805 us; speedup 1.0000x reference)
//
#include <hip/hip_runtime.h>

#pragma clang fp contract(off)

#define B_  4
#define N_  16384
#define NQ_ 1024
#define C_  128
#define NS_ 64

// ---------------------------------------------------------------------------
// Transpose key_features [B][C][N] -> [B][N][C] into workspace so the per-query
// gather reads 512B contiguous rows instead of 64 scattered 4B elements.
// ---------------------------------------------------------------------------
__global__ __launch_bounds__(256) void transpose_feat(const float* __restrict__ in,
                                                      float* __restrict__ out) {
    __shared__ float t[32][33];
    int b  = blockIdx.z;
    int c0 = blockIdx.y * 32;
    int n0 = blockIdx.x * 32;
    int x = threadIdx.x;   // 0..31
    int y = threadIdx.y;   // 0..7
#pragma unroll
    for (int k = 0; k < 4; ++k) {
        // t[cc][nn] = in[b][c0+cc][n0+nn], coalesced along n
        t[y + 8*k][x] = in[((size_t)b * C_ + c0 + y + 8*k) * N_ + n0 + x];
    }
    __syncthreads();
#pragma unroll
    for (int k = 0; k < 4; ++k) {
        // out[b][n0+nn][c0+cc] = t[cc][nn], coalesced along c
        out[((size_t)b * N_ + n0 + y + 8*k) * C_ + c0 + x] = t[x][y + 8*k];
    }
}

// ---------------------------------------------------------------------------
// One 256-thread block per (b,q).
// Phase 1: 4 waves scan N/4 contiguous segments each, building ordered
//          candidate lists (inside-box and within-radius) via ballot+popc.
// Merge:   wave 0 concatenates per-wave lists in segment order (stable-argsort
//          semantics), emits idx[], mask, grouped_xyz.
// Phase 2: gather 64x128 feature tile (from transposed features if available),
//          stage in LDS, write coalesced to [C][NQ][NS] layout.
// ---------------------------------------------------------------------------
__global__ __launch_bounds__(256) void boxgroup(
    const float* __restrict__ key_xyz, const float* __restrict__ key_feat,
    const float* __restrict__ query,   const float* __restrict__ feat_t,
    float* __restrict__ out_xyz, float* __restrict__ out_feat,
    float* __restrict__ out_mask, int use_t)
{
    const float R2 = (float)(0.3 * 0.3);
    int bq = blockIdx.x;
    int b  = bq >> 10;       // NQ_ = 1024
    int q  = bq & (NQ_ - 1);
    int t    = threadIdx.x;
    int wave = t >> 6;
    int lane = t & 63;

    __shared__ int   s_in[4][NS_];
    __shared__ int   s_rad[4][NS_];
    __shared__ int   s_cin[4], s_crad[4];
    __shared__ int   s_idx[NS_];
    __shared__ float tile[NS_][129];   // pad 129: (lane*129+c)%32 = (lane+c)%32 -> conflict-free readout

    const float* qp = query + (size_t)bq * 6;
    float cx = qp[0], cy = qp[1], cz = qp[2];
    float hx = 0.5f * qp[3], hy = 0.5f * qp[4], hz = 0.5f * qp[5];

    const float* kb = key_xyz + (size_t)b * N_ * 3;

    int cin = 0, crad = 0;
    const int seg = N_ / 4;            // 4096 per wave
    int n0 = wave * seg;
    for (int it = 0; it < seg / 64; ++it) {
        int n = n0 + it * 64 + lane;
        float x = kb[3*n + 0];
        float y = kb[3*n + 1];
        float z = kb[3*n + 2];
        float dx = fabsf(x - cx), dy = fabsf(y - cy), dz = fabsf(z - cz);
        bool inside = (dx <= hx) && (dy <= hy) && (dz <= hz);
        float d2 = dx*dx + dy*dy + dz*dz;     // contraction off: matches numpy f32
        bool rad = d2 <= R2;
        unsigned long long mi = __ballot(inside);
        unsigned long long mr = __ballot(rad);
        unsigned long long lt = (1ull << lane) - 1ull;
        if (inside) { int p = cin  + __popcll(mi & lt); if (p < NS_) s_in[wave][p]  = n; }
        if (rad)    { int p = crad + __popcll(mr & lt); if (p < NS_) s_rad[wave][p] = n; }
        cin  += __popcll(mi);
        crad += __popcll(mr);
    }
    if (lane == 0) { s_cin[wave] = cin; s_crad[wave] = crad; }
    __syncthreads();

    if (wave == 0) {
        int ti = s_cin[0] + s_cin[1] + s_cin[2] + s_cin[3];
        bool has_box = ti > 0;
        const int (*lists)[NS_] = has_box ? s_in : s_rad;
        const int* cnts         = has_box ? s_cin : s_crad;
        int c0s = min(cnts[0], NS_);
        int c1s = min(cnts[1], NS_);
        int c2s = min(cnts[2], NS_);
        int tot   = cnts[0] + cnts[1] + cnts[2] + cnts[3];
        int count = min(tot, NS_);
        int j = lane;
        int idx = 0;
        if (j < count) {
            int o1 = c0s, o2 = o1 + c1s, o3 = o2 + c2s;
            if      (j < o1) idx = lists[0][j];
            else if (j < o2) idx = lists[1][j - o1];
            else if (j < o3) idx = lists[2][j - o2];
            else             idx = lists[3][j - o3];
        }
        s_idx[j] = idx;
        out_mask[(size_t)bq * NS_ + j] = (j >= count && j > 0) ? 1.0f : 0.0f;
        float px = kb[3*idx + 0] - cx;
        float py = kb[3*idx + 1] - cy;
        float pz = kb[3*idx + 2] - cz;
        size_t xb = ((size_t)b * 3) * NQ_ * NS_ + (size_t)q * NS_ + j;
        out_xyz[xb]                        = px;
        out_xyz[xb +     (size_t)NQ_*NS_]  = py;
        out_xyz[xb + 2 * (size_t)NQ_*NS_]  = pz;
    }
    __syncthreads();

    float* ob = out_feat + (size_t)b * C_ * NQ_ * NS_ + (size_t)q * NS_;
    if (use_t) {
        // coalesced gather: each u reads one float4 (4 consecutive c) of row idx[j]
        const float4* ft4 = (const float4*)feat_t;
#pragma unroll
        for (int itr = 0; itr < 8; ++itr) {
            int u  = t + itr * 256;
            int j  = u >> 5;
            int c4 = u & 31;
            float4 v = ft4[((size_t)b * N_ + s_idx[j]) * (C_ / 4) + c4];
            tile[j][c4*4 + 0] = v.x;
            tile[j][c4*4 + 1] = v.y;
            tile[j][c4*4 + 2] = v.z;
            tile[j][c4*4 + 3] = v.w;
        }
        __syncthreads();
        for (int c = wave; c < C_; c += 4) {
            ob[(size_t)c * NQ_ * NS_ + lane] = tile[lane][c];   // 256B coalesced store
        }
    } else {
        // fallback: direct scattered gather from [C][N]
        const float* fb = key_feat + (size_t)b * C_ * N_;
        int idx = s_idx[lane];
        for (int c = wave; c < C_; c += 4) {
            ob[(size_t)c * NQ_ * NS_ + lane] = fb[(size_t)c * N_ + idx];
        }
    }
}

extern "C" void kernel_launch(void* const* d_in, const int* in_sizes, int n_in,
                              void* d_out, int out_size, void* d_ws, size_t ws_size,
                              hipStream_t stream) {
    const float* key_xyz  = (const float*)d_in[0];
    const float* key_feat = (const float*)d_in[1];
    const float* query    = (const float*)d_in[2];

    float* out      = (float*)d_out;
    float* out_xyz  = out;
    float* out_feat = out + (size_t)B_ * 3 * NQ_ * NS_;
    float* out_mask = out_feat + (size_t)B_ * C_ * NQ_ * NS_;

    size_t tsz = (size_t)B_ * N_ * C_ * sizeof(float);
    int use_t = (ws_size >= tsz) ? 1 : 0;
    float* ft = (float*)d_ws;

    if (use_t) {
        dim3 g(N_ / 32, C_ / 32, B_);
        dim3 blk(32, 8, 1);
        transpose_feat<<<g, blk, 0, stream>>>(key_feat, ft);
    }
    boxgroup<<<dim3(B_ * NQ_), dim3(256), 0, stream>>>(
        key_xyz, key_feat, query, ft, out_xyz, out_feat, out_mask, use_t);
}

// Round 2
// 247.892 us; speedup vs baseline: 1.2256x; 1.2256x over previous
//
#include <hip/hip_runtime.h>

#pragma clang fp contract(off)

#define B_  4
#define N_  16384
#define NQ_ 1024
#define C_  128
#define NS_ 64

// ---------------------------------------------------------------------------
// Transpose key_features [B][C][N] -> [B][N][C] in d_ws so the per-query
// gather reads 512B contiguous rows instead of 64 scattered 4B elements.
// ---------------------------------------------------------------------------
__global__ __launch_bounds__(256) void transpose_feat(const float* __restrict__ in,
                                                      float* __restrict__ out) {
    __shared__ float t[32][33];
    int b  = blockIdx.z;
    int c0 = blockIdx.y * 32;
    int n0 = blockIdx.x * 32;
    int x = threadIdx.x;   // 0..31
    int y = threadIdx.y;   // 0..7
#pragma unroll
    for (int k = 0; k < 4; ++k)
        t[y + 8*k][x] = in[((size_t)b * C_ + c0 + y + 8*k) * N_ + n0 + x];
    __syncthreads();
#pragma unroll
    for (int k = 0; k < 4; ++k)
        out[((size_t)b * N_ + n0 + y + 8*k) * C_ + c0 + x] = t[x][y + 8*k];
}

// ---------------------------------------------------------------------------
// Selection: one 256-thread block per (b,q). Tiny LDS -> full occupancy.
// Pass 1: inside-box only (cheap). Pass 2 (radius) only if no box point.
// Per-wave early exit once its ordered list holds >=64 candidates.
// ---------------------------------------------------------------------------
__global__ __launch_bounds__(256) void select_k(
    const float* __restrict__ key_xyz, const float* __restrict__ query,
    int* __restrict__ idx_out, float* __restrict__ out_xyz,
    float* __restrict__ out_mask)
{
    int bq = blockIdx.x;
    int b  = bq >> 10;          // NQ_ = 1024
    int q  = bq & (NQ_ - 1);
    int t    = threadIdx.x;
    int wave = t >> 6;
    int lane = t & 63;

    __shared__ int s_list[4][NS_];
    __shared__ int s_cnt[4];

    const float* qp = query + (size_t)bq * 6;
    float cx = qp[0], cy = qp[1], cz = qp[2];
    float hx = 0.5f * qp[3], hy = 0.5f * qp[4], hz = 0.5f * qp[5];
    const float* kb = key_xyz + (size_t)b * N_ * 3;

    const int seg = N_ / 4;     // 4096 points per wave, contiguous segment
    int n0 = wave * seg;
    unsigned long long lt = (1ull << lane) - 1ull;

    int cnt = 0;
    for (int it = 0; it < seg / 64; ++it) {
        int n = n0 + it * 64 + lane;
        float dx = fabsf(kb[3*n + 0] - cx);
        float dy = fabsf(kb[3*n + 1] - cy);
        float dz = fabsf(kb[3*n + 2] - cz);
        bool inside = (dx <= hx) && (dy <= hy) && (dz <= hz);
        unsigned long long m = __ballot(inside);
        if (inside) {
            int p = cnt + __popcll(m & lt);
            if (p < NS_) s_list[wave][p] = n;
        }
        cnt += __popcll(m);
        if (cnt >= NS_) break;          // list full; min(.,64) math unaffected
    }
    if (lane == 0) s_cnt[wave] = cnt;
    __syncthreads();

    int ti = s_cnt[0] + s_cnt[1] + s_cnt[2] + s_cnt[3];
    if (ti == 0) {                      // rare: no box point -> radius select
        const float R2 = (float)(0.3 * 0.3);
        cnt = 0;
        for (int it = 0; it < seg / 64; ++it) {
            int n = n0 + it * 64 + lane;
            float dx = kb[3*n + 0] - cx;
            float dy = kb[3*n + 1] - cy;
            float dz = kb[3*n + 2] - cz;
            float d2 = dx*dx + dy*dy + dz*dz;   // contract off: matches numpy
            bool r = d2 <= R2;
            unsigned long long m = __ballot(r);
            if (r) {
                int p = cnt + __popcll(m & lt);
                if (p < NS_) s_list[wave][p] = n;
            }
            cnt += __popcll(m);
            if (cnt >= NS_) break;
        }
        if (lane == 0) s_cnt[wave] = cnt;
    }
    __syncthreads();

    if (wave == 0) {
        int c0s = min(s_cnt[0], NS_);
        int c1s = min(s_cnt[1], NS_);
        int c2s = min(s_cnt[2], NS_);
        int tot   = s_cnt[0] + s_cnt[1] + s_cnt[2] + s_cnt[3];
        int count = min(tot, NS_);
        int j = lane;
        int idx = 0;
        if (j < count) {
            int o1 = c0s, o2 = o1 + c1s, o3 = o2 + c2s;
            if      (j < o1) idx = s_list[0][j];
            else if (j < o2) idx = s_list[1][j - o1];
            else if (j < o3) idx = s_list[2][j - o2];
            else             idx = s_list[3][j - o3];
        }
        idx_out[(size_t)bq * NS_ + j] = idx;
        out_mask[(size_t)bq * NS_ + j] = (j >= count && j > 0) ? 1.0f : 0.0f;
        float px = kb[3*idx + 0] - cx;
        float py = kb[3*idx + 1] - cy;
        float pz = kb[3*idx + 2] - cz;
        size_t xb = ((size_t)b * 3) * NQ_ * NS_ + (size_t)q * NS_ + j;
        out_xyz[xb]                       = px;
        out_xyz[xb +     (size_t)NQ_*NS_] = py;
        out_xyz[xb + 2 * (size_t)NQ_*NS_] = pz;
    }
}

// ---------------------------------------------------------------------------
// Gather: one 512-thread block per (b,q); 33KB tile -> 4 blocks x 8 waves
// = 32 waves/CU (full occupancy). Coalesced float4 gather -> LDS -> coalesced
// nontemporal stores to [C][NQ][NS].
// ---------------------------------------------------------------------------
__global__ __launch_bounds__(512) void gather_k(
    const float* __restrict__ feat_t, const int* __restrict__ idx_in,
    const float* __restrict__ key_feat, float* __restrict__ out_feat, int use_t)
{
    int bq = blockIdx.x;
    int b  = bq >> 10;
    int q  = bq & (NQ_ - 1);
    int t    = threadIdx.x;
    int wave = t >> 6;
    int lane = t & 63;

    __shared__ int   s_idx[NS_];
    __shared__ float tile[NS_][129];   // readout (lane*129+c)%32 conflict-free

    if (t < NS_) s_idx[t] = idx_in[(size_t)bq * NS_ + t];
    __syncthreads();

    float* ob = out_feat + (size_t)b * C_ * NQ_ * NS_ + (size_t)q * NS_;
    if (use_t) {
        const float4* ft4 = (const float4*)feat_t;
#pragma unroll
        for (int k = 0; k < 4; ++k) {
            int u  = t + k * 512;
            int j  = u >> 5;
            int c4 = u & 31;
            float4 v = ft4[((size_t)b * N_ + s_idx[j]) * (C_ / 4) + c4];
            tile[j][c4*4 + 0] = v.x;
            tile[j][c4*4 + 1] = v.y;
            tile[j][c4*4 + 2] = v.z;
            tile[j][c4*4 + 3] = v.w;
        }
        __syncthreads();
#pragma unroll
        for (int c = wave; c < C_; c += 8)
            __builtin_nontemporal_store(tile[lane][c],
                                        &ob[(size_t)c * NQ_ * NS_ + lane]);
    } else {
        const float* fb = key_feat + (size_t)b * C_ * N_;
        int idx = s_idx[lane];
        for (int c = wave; c < C_; c += 8)
            ob[(size_t)c * NQ_ * NS_ + lane] = fb[(size_t)c * N_ + idx];
    }
}

extern "C" void kernel_launch(void* const* d_in, const int* in_sizes, int n_in,
                              void* d_out, int out_size, void* d_ws, size_t ws_size,
                              hipStream_t stream) {
    const float* key_xyz  = (const float*)d_in[0];
    const float* key_feat = (const float*)d_in[1];
    const float* query    = (const float*)d_in[2];

    float* out      = (float*)d_out;
    float* out_xyz  = out;
    float* out_feat = out + (size_t)B_ * 3 * NQ_ * NS_;
    float* out_mask = out_feat + (size_t)B_ * C_ * NQ_ * NS_;

    // ws layout: [idx: B*NQ*NS ints = 1MB][feat_t: B*N*C floats = 33.5MB]
    size_t idx_bytes = (size_t)B_ * NQ_ * NS_ * sizeof(int);
    size_t tsz       = (size_t)B_ * N_ * C_ * sizeof(float);
    int*   d_idx = (int*)d_ws;
    float* ft    = (float*)((char*)d_ws + idx_bytes);
    int use_t = (ws_size >= idx_bytes + tsz) ? 1 : 0;

    if (use_t) {
        dim3 g(N_ / 32, C_ / 32, B_);
        dim3 blk(32, 8, 1);
        transpose_feat<<<g, blk, 0, stream>>>(key_feat, ft);
    }
    select_k<<<dim3(B_ * NQ_), dim3(256), 0, stream>>>(
        key_xyz, query, d_idx, out_xyz, out_mask);
    gather_k<<<dim3(B_ * NQ_), dim3(512), 0, stream>>>(
        ft, d_idx, key_feat, out_feat, use_t);
}

// Round 3
// 216.576 us; speedup vs baseline: 1.4028x; 1.1446x over previous
//
#include <hip/hip_runtime.h>

#pragma clang fp contract(off)

#define B_  4
#define N_  16384
#define NQ_ 1024
#define C_  128
#define NS_ 64
#define G_  16          // grid cells per dim
#define NCELL_ 4096     // G^3
#define MAXCELLS_ 344   // 7^3 max overlapped cells (+1 slack)
#define SELCAP_ 1024    // selected-list capacity (mean max ~256, +48 sigma safe)

// ---- workspace layout (bytes) ----
#define OFF_IDX    ((size_t)0)
#define SZ_IDX     ((size_t)B_*NQ_*NS_*4)
#define OFF_FEAT   ((size_t)(1u<<20))
#define SZ_FEAT    ((size_t)B_*N_*C_*4)
#define OFF_COUNTS (OFF_FEAT + SZ_FEAT)
#define OFF_CSTART (OFF_COUNTS + (size_t)B_*NCELL_*4)
#define OFF_CURSOR (OFF_CSTART + (size_t)B_*NCELL_*4)
#define OFF_PLIST  (OFF_CURSOR + (size_t)B_*NCELL_*4)
#define WS_NEED    (OFF_PLIST + (size_t)B_*N_*4)

// ---------------------------------------------------------------------------
// Binning: zero counts -> atomic count -> per-batch scan -> atomic scatter.
// Within-cell order is nondeterministic; the per-query sort restores the
// exact stable-argsort (ascending index) semantics.
// ---------------------------------------------------------------------------
__global__ __launch_bounds__(256) void zero_k(int* __restrict__ counts) {
    int id = blockIdx.x * 256 + threadIdx.x;
    if (id < B_ * NCELL_) counts[id] = 0;
}

__device__ __forceinline__ int cell_of(float x, float y, float z) {
    int ix = (int)(x * (float)G_); ix = min(G_ - 1, max(0, ix));
    int iy = (int)(y * (float)G_); iy = min(G_ - 1, max(0, iy));
    int iz = (int)(z * (float)G_); iz = min(G_ - 1, max(0, iz));
    return ix + (iy << 4) + (iz << 8);
}

__global__ __launch_bounds__(256) void bin_count_k(const float* __restrict__ key_xyz,
                                                   int* __restrict__ counts) {
    int id = blockIdx.x * 256 + threadIdx.x;   // < B*N
    int b = id >> 14, n = id & (N_ - 1);
    const float* p = key_xyz + ((size_t)b * N_ + n) * 3;
    int cid = cell_of(p[0], p[1], p[2]);
    atomicAdd(&counts[(b << 12) + cid], 1);
}

__global__ __launch_bounds__(1024) void scan_k(const int* __restrict__ counts,
                                               int* __restrict__ cstart,
                                               int* __restrict__ cursor) {
    __shared__ int a[1024];
    int b = blockIdx.x, t = threadIdx.x;
    int base = b << 12;
    int c0 = t * 4;
    int v0 = counts[base + c0 + 0], v1 = counts[base + c0 + 1];
    int v2 = counts[base + c0 + 2], v3 = counts[base + c0 + 3];
    int s = v0 + v1 + v2 + v3;
    a[t] = s;
    __syncthreads();
    for (int o = 1; o < 1024; o <<= 1) {
        int add = (t >= o) ? a[t - o] : 0;
        __syncthreads();
        a[t] += add;
        __syncthreads();
    }
    int excl = a[t] - s;
    int e0 = excl, e1 = e0 + v0, e2 = e1 + v1, e3 = e2 + v2;
    cstart[base + c0 + 0] = e0; cursor[base + c0 + 0] = e0;
    cstart[base + c0 + 1] = e1; cursor[base + c0 + 1] = e1;
    cstart[base + c0 + 2] = e2; cursor[base + c0 + 2] = e2;
    cstart[base + c0 + 3] = e3; cursor[base + c0 + 3] = e3;
}

__global__ __launch_bounds__(256) void scatter_k(const float* __restrict__ key_xyz,
                                                 int* __restrict__ cursor,
                                                 int* __restrict__ plist) {
    int id = blockIdx.x * 256 + threadIdx.x;
    int b = id >> 14, n = id & (N_ - 1);
    const float* p = key_xyz + ((size_t)b * N_ + n) * 3;
    int cid = cell_of(p[0], p[1], p[2]);
    int pos = atomicAdd(&cursor[(b << 12) + cid], 1);   // batch-local absolute
    plist[(b << 14) + pos] = n;
}

// ---------------------------------------------------------------------------
// Fused kernel: blocks [0, 4096) do grid-based selection (one block per (b,q));
// blocks [4096, 12288) transpose key_features [B][C][N] -> [B][N][C].
// Overlaps BW-bound transpose with VALU-bound select.
// ---------------------------------------------------------------------------
__global__ __launch_bounds__(256) void fused_ts_k(
    const float* __restrict__ key_xyz, const float* __restrict__ key_feat,
    const float* __restrict__ query,
    const int* __restrict__ counts, const int* __restrict__ cstart,
    const int* __restrict__ plist,
    float* __restrict__ feat_t, int* __restrict__ idx_out,
    float* __restrict__ out_xyz, float* __restrict__ out_mask)
{
    __shared__ float ttile[32][33];            // transpose path
    __shared__ int s_ccnt[MAXCELLS_];          // select path
    __shared__ int s_cstart[MAXCELLS_];
    __shared__ int s_pref[MAXCELLS_ + 1];
    __shared__ int s_sel[SELCAP_];
    __shared__ int s_scnt;
    __shared__ int s_list[4][NS_];             // radius fallback
    __shared__ int s_cnt4[4];

    int t = threadIdx.x;

    if (blockIdx.x >= B_ * NQ_) {
        // ---------------- transpose ----------------
        int id2 = blockIdx.x - B_ * NQ_;       // < 8192
        int n0 = (id2 & 511) * 32;
        int c0 = ((id2 >> 9) & 3) * 32;
        int b  = id2 >> 11;
        int x = t & 31, y = t >> 5;            // 32 x 8
#pragma unroll
        for (int k = 0; k < 4; ++k)
            ttile[y + 8*k][x] = key_feat[((size_t)b * C_ + c0 + y + 8*k) * N_ + n0 + x];
        __syncthreads();
#pragma unroll
        for (int k = 0; k < 4; ++k)
            feat_t[((size_t)b * N_ + n0 + y + 8*k) * C_ + c0 + x] = ttile[x][y + 8*k];
        return;
    }

    // ---------------- selection ----------------
    int bq = blockIdx.x;
    int b  = bq >> 10;
    int q  = bq & (NQ_ - 1);
    int wave = t >> 6, lane = t & 63;

    const float* qp = query + (size_t)bq * 6;
    float cx = qp[0], cy = qp[1], cz = qp[2];
    float hx = 0.5f * qp[3], hy = 0.5f * qp[4], hz = 0.5f * qp[5];
    const float* kb = key_xyz + (size_t)b * N_ * 3;

    if (t == 0) s_scnt = 0;

    // cells overlapping the box, expanded by 1 cell (float-boundary safety)
    int ilox = max(0, (int)floorf((cx - hx) * (float)G_) - 1);
    int ihix = min(G_ - 1, (int)floorf((cx + hx) * (float)G_) + 1);
    int iloy = max(0, (int)floorf((cy - hy) * (float)G_) - 1);
    int ihiy = min(G_ - 1, (int)floorf((cy + hy) * (float)G_) + 1);
    int iloz = max(0, (int)floorf((cz - hz) * (float)G_) - 1);
    int ihiz = min(G_ - 1, (int)floorf((cz + hz) * (float)G_) + 1);
    int nx = ihix - ilox + 1, ny = ihiy - iloy + 1, nz = ihiz - iloz + 1;
    int ncells = nx * ny * nz;                 // <= 343

    for (int ci = t; ci < ncells; ci += 256) {
        int iz = ci / (nx * ny);
        int r  = ci - iz * (nx * ny);
        int iy = r / nx;
        int ix = r - iy * nx;
        int cid = (ilox + ix) + ((iloy + iy) << 4) + ((iloz + iz) << 8);
        s_ccnt[ci]   = counts[(b << 12) + cid];
        s_cstart[ci] = cstart[(b << 12) + cid];
    }
    __syncthreads();

    // exclusive prefix over <=343 cell counts (wave 0)
    if (wave == 0) {
        int run = 0;
        for (int base = 0; base < ncells; base += 64) {
            int x = (base + lane < ncells) ? s_ccnt[base + lane] : 0;
            int own = x;
#pragma unroll
            for (int o = 1; o < 64; o <<= 1) {
                int v = __shfl_up(x, (unsigned)o);
                if (lane >= o) x += v;
            }
            if (base + lane < ncells) s_pref[base + lane] = run + x - own;
            run += __shfl(x, 63);
        }
        if (lane == 0) s_pref[ncells] = run;
    }
    __syncthreads();

    int total = s_pref[ncells];
    for (int i = t; i < total; i += 256) {
        int lo = 0, hi = ncells;              // find cell: pref[lo] <= i < pref[lo+1]
        while (hi - lo > 1) {
            int mid = (lo + hi) >> 1;
            if (s_pref[mid] <= i) lo = mid; else hi = mid;
        }
        int n = plist[(b << 14) + s_cstart[lo] + (i - s_pref[lo])];
        float dx = fabsf(kb[3*n + 0] - cx);
        float dy = fabsf(kb[3*n + 1] - cy);
        float dz = fabsf(kb[3*n + 2] - cz);
        if (dx <= hx && dy <= hy && dz <= hz) {
            int pos = atomicAdd(&s_scnt, 1);
            if (pos < SELCAP_) s_sel[pos] = n;
        }
    }
    __syncthreads();
    int scnt = s_scnt;

    if (scnt > 0) {
        // sort selected ascending -> exact stable-argsort order
        int m = 64;
        while (m < scnt && m < SELCAP_) m <<= 1;
        for (int i = t; i < m; i += 256)
            if (i >= scnt) s_sel[i] = 0x7fffffff;
        __syncthreads();
        for (int k = 2; k <= m; k <<= 1) {
            for (int j = k >> 1; j > 0; j >>= 1) {
                for (int i = t; i < m; i += 256) {
                    int ixj = i ^ j;
                    if (ixj > i) {
                        int va = s_sel[i], vb = s_sel[ixj];
                        bool up = ((i & k) == 0);
                        if ((va > vb) == up) { s_sel[i] = vb; s_sel[ixj] = va; }
                    }
                }
                __syncthreads();
            }
        }
        int count = min(scnt, NS_);
        if (t < NS_) {
            int j = t;
            int idx = (j < count) ? s_sel[j] : 0;
            idx_out[(size_t)bq * NS_ + j] = idx;
            out_mask[(size_t)bq * NS_ + j] = (j >= count && j > 0) ? 1.0f : 0.0f;
            float px = kb[3*idx + 0] - cx;
            float py = kb[3*idx + 1] - cy;
            float pz = kb[3*idx + 2] - cz;
            size_t xb = ((size_t)b * 3) * NQ_ * NS_ + (size_t)q * NS_ + j;
            out_xyz[xb]                       = px;
            out_xyz[xb +     (size_t)NQ_*NS_] = py;
            out_xyz[xb + 2 * (size_t)NQ_*NS_] = pz;
        }
    } else {
        // radius fallback: ordered segment scan (round-2 verified path)
        const float R2 = (float)(0.3 * 0.3);
        const int seg = N_ / 4;
        int n0s = wave * seg;
        unsigned long long lt = (1ull << lane) - 1ull;
        int cnt = 0;
        for (int it = 0; it < seg / 64; ++it) {
            int n = n0s + it * 64 + lane;
            float dx = kb[3*n + 0] - cx;
            float dy = kb[3*n + 1] - cy;
            float dz = kb[3*n + 2] - cz;
            float d2 = dx*dx + dy*dy + dz*dz;   // contract off: matches numpy
            bool r = d2 <= R2;
            unsigned long long mmask = __ballot(r);
            if (r) {
                int p = cnt + __popcll(mmask & lt);
                if (p < NS_) s_list[wave][p] = n;
            }
            cnt += __popcll(mmask);
            if (cnt >= NS_) break;
        }
        if (lane == 0) s_cnt4[wave] = cnt;
        __syncthreads();
        if (wave == 0) {
            int c0s = min(s_cnt4[0], NS_);
            int c1s = min(s_cnt4[1], NS_);
            int c2s = min(s_cnt4[2], NS_);
            int tot   = s_cnt4[0] + s_cnt4[1] + s_cnt4[2] + s_cnt4[3];
            int count = min(tot, NS_);
            int j = lane;
            int idx = 0;
            if (j < count) {
                int o1 = c0s, o2 = o1 + c1s, o3 = o2 + c2s;
                if      (j < o1) idx = s_list[0][j];
                else if (j < o2) idx = s_list[1][j - o1];
                else if (j < o3) idx = s_list[2][j - o2];
                else             idx = s_list[3][j - o3];
            }
            idx_out[(size_t)bq * NS_ + j] = idx;
            out_mask[(size_t)bq * NS_ + j] = (j >= count && j > 0) ? 1.0f : 0.0f;
            float px = kb[3*idx + 0] - cx;
            float py = kb[3*idx + 1] - cy;
            float pz = kb[3*idx + 2] - cz;
            size_t xb = ((size_t)b * 3) * NQ_ * NS_ + (size_t)q * NS_ + j;
            out_xyz[xb]                       = px;
            out_xyz[xb +     (size_t)NQ_*NS_] = py;
            out_xyz[xb + 2 * (size_t)NQ_*NS_] = pz;
        }
    }
}

// ---------------------------------------------------------------------------
// Fallback linear select (used only if ws is too small for binning tables).
// ---------------------------------------------------------------------------
__global__ __launch_bounds__(256) void select_lin_k(
    const float* __restrict__ key_xyz, const float* __restrict__ query,
    int* __restrict__ idx_out, float* __restrict__ out_xyz,
    float* __restrict__ out_mask)
{
    int bq = blockIdx.x;
    int b  = bq >> 10;
    int q  = bq & (NQ_ - 1);
    int t    = threadIdx.x;
    int wave = t >> 6;
    int lane = t & 63;

    __shared__ int s_list[4][NS_];
    __shared__ int s_cnt[4];

    const float* qp = query + (size_t)bq * 6;
    float cx = qp[0], cy = qp[1], cz = qp[2];
    float hx = 0.5f * qp[3], hy = 0.5f * qp[4], hz = 0.5f * qp[5];
    const float* kb = key_xyz + (size_t)b * N_ * 3;

    const int seg = N_ / 4;
    int n0 = wave * seg;
    unsigned long long lt = (1ull << lane) - 1ull;

    int cnt = 0;
    for (int it = 0; it < seg / 64; ++it) {
        int n = n0 + it * 64 + lane;
        float dx = fabsf(kb[3*n + 0] - cx);
        float dy = fabsf(kb[3*n + 1] - cy);
        float dz = fabsf(kb[3*n + 2] - cz);
        bool inside = (dx <= hx) && (dy <= hy) && (dz <= hz);
        unsigned long long m = __ballot(inside);
        if (inside) {
            int p = cnt + __popcll(m & lt);
            if (p < NS_) s_list[wave][p] = n;
        }
        cnt += __popcll(m);
        if (cnt >= NS_) break;
    }
    if (lane == 0) s_cnt[wave] = cnt;
    __syncthreads();

    int ti = s_cnt[0] + s_cnt[1] + s_cnt[2] + s_cnt[3];
    if (ti == 0) {
        const float R2 = (float)(0.3 * 0.3);
        cnt = 0;
        for (int it = 0; it < seg / 64; ++it) {
            int n = n0 + it * 64 + lane;
            float dx = kb[3*n + 0] - cx;
            float dy = kb[3*n + 1] - cy;
            float dz = kb[3*n + 2] - cz;
            float d2 = dx*dx + dy*dy + dz*dz;
            bool r = d2 <= R2;
            unsigned long long m = __ballot(r);
            if (r) {
                int p = cnt + __popcll(m & lt);
                if (p < NS_) s_list[wave][p] = n;
            }
            cnt += __popcll(m);
            if (cnt >= NS_) break;
        }
        if (lane == 0) s_cnt[wave] = cnt;
    }
    __syncthreads();

    if (wave == 0) {
        int c0s = min(s_cnt[0], NS_);
        int c1s = min(s_cnt[1], NS_);
        int c2s = min(s_cnt[2], NS_);
        int tot   = s_cnt[0] + s_cnt[1] + s_cnt[2] + s_cnt[3];
        int count = min(tot, NS_);
        int j = lane;
        int idx = 0;
        if (j < count) {
            int o1 = c0s, o2 = o1 + c1s, o3 = o2 + c2s;
            if      (j < o1) idx = s_list[0][j];
            else if (j < o2) idx = s_list[1][j - o1];
            else if (j < o3) idx = s_list[2][j - o2];
            else             idx = s_list[3][j - o3];
        }
        idx_out[(size_t)bq * NS_ + j] = idx;
        out_mask[(size_t)bq * NS_ + j] = (j >= count && j > 0) ? 1.0f : 0.0f;
        float px = kb[3*idx + 0] - cx;
        float py = kb[3*idx + 1] - cy;
        float pz = kb[3*idx + 2] - cz;
        size_t xb = ((size_t)b * 3) * NQ_ * NS_ + (size_t)q * NS_ + j;
        out_xyz[xb]                       = px;
        out_xyz[xb +     (size_t)NQ_*NS_] = py;
        out_xyz[xb + 2 * (size_t)NQ_*NS_] = pz;
    }
}

// ---------------------------------------------------------------------------
// Gather: one 512-thread block per (b,q); coalesced float4 row gather -> LDS
// -> coalesced nontemporal stores to [C][NQ][NS]. (unchanged from round 2)
// ---------------------------------------------------------------------------
__global__ __launch_bounds__(512) void gather_k(
    const float* __restrict__ feat_t, const int* __restrict__ idx_in,
    const float* __restrict__ key_feat, float* __restrict__ out_feat, int use_t)
{
    int bq = blockIdx.x;
    int b  = bq >> 10;
    int q  = bq & (NQ_ - 1);
    int t    = threadIdx.x;
    int wave = t >> 6;
    int lane = t & 63;

    __shared__ int   s_idx[NS_];
    __shared__ float tile[NS_][129];

    if (t < NS_) s_idx[t] = idx_in[(size_t)bq * NS_ + t];
    __syncthreads();

    float* ob = out_feat + (size_t)b * C_ * NQ_ * NS_ + (size_t)q * NS_;
    if (use_t) {
        const float4* ft4 = (const float4*)feat_t;
#pragma unroll
        for (int k = 0; k < 4; ++k) {
            int u  = t + k * 512;
            int j  = u >> 5;
            int c4 = u & 31;
            float4 v = ft4[((size_t)b * N_ + s_idx[j]) * (C_ / 4) + c4];
            tile[j][c4*4 + 0] = v.x;
            tile[j][c4*4 + 1] = v.y;
            tile[j][c4*4 + 2] = v.z;
            tile[j][c4*4 + 3] = v.w;
        }
        __syncthreads();
#pragma unroll
        for (int c = wave; c < C_; c += 8)
            __builtin_nontemporal_store(tile[lane][c],
                                        &ob[(size_t)c * NQ_ * NS_ + lane]);
    } else {
        const float* fb = key_feat + (size_t)b * C_ * N_;
        int idx = s_idx[lane];
        for (int c = wave; c < C_; c += 8)
            ob[(size_t)c * NQ_ * NS_ + lane] = fb[(size_t)c * N_ + idx];
    }
}

extern "C" void kernel_launch(void* const* d_in, const int* in_sizes, int n_in,
                              void* d_out, int out_size, void* d_ws, size_t ws_size,
                              hipStream_t stream) {
    const float* key_xyz  = (const float*)d_in[0];
    const float* key_feat = (const float*)d_in[1];
    const float* query    = (const float*)d_in[2];

    float* out      = (float*)d_out;
    float* out_xyz  = out;
    float* out_feat = out + (size_t)B_ * 3 * NQ_ * NS_;
    float* out_mask = out_feat + (size_t)B_ * C_ * NQ_ * NS_;

    char* ws = (char*)d_ws;
    int*   d_idx   = (int*)(ws + OFF_IDX);
    float* ft      = (float*)(ws + OFF_FEAT);
    int*   counts  = (int*)(ws + OFF_COUNTS);
    int*   cstartp = (int*)(ws + OFF_CSTART);
    int*   cursor  = (int*)(ws + OFF_CURSOR);
    int*   plist   = (int*)(ws + OFF_PLIST);

    if (ws_size >= WS_NEED) {
        zero_k<<<dim3((B_ * NCELL_ + 255) / 256), dim3(256), 0, stream>>>(counts);
        bin_count_k<<<dim3(B_ * N_ / 256), dim3(256), 0, stream>>>(key_xyz, counts);
        scan_k<<<dim3(B_), dim3(1024), 0, stream>>>(counts, cstartp, cursor);
        scatter_k<<<dim3(B_ * N_ / 256), dim3(256), 0, stream>>>(key_xyz, cursor, plist);
        fused_ts_k<<<dim3(B_ * NQ_ + B_ * (C_ / 32) * (N_ / 32)), dim3(256), 0, stream>>>(
            key_xyz, key_feat, query, counts, cstartp, plist,
            ft, d_idx, out_xyz, out_mask);
        gather_k<<<dim3(B_ * NQ_), dim3(512), 0, stream>>>(
            ft, d_idx, key_feat, out_feat, 1);
    } else {
        // minimal-workspace fallback (only d_idx needed)
        select_lin_k<<<dim3(B_ * NQ_), dim3(256), 0, stream>>>(
            key_xyz, query, d_idx, out_xyz, out_mask);
        gather_k<<<dim3(B_ * NQ_), dim3(512), 0, stream>>>(
            ft, d_idx, key_feat, out_feat, 0);
    }
}

// Round 4
// 211.025 us; speedup vs baseline: 1.4397x; 1.0263x over previous
//
#include <hip/hip_runtime.h>

#pragma clang fp contract(off)

#define B_  4
#define N_  16384
#define NQ_ 1024
#define C_  128
#define NS_ 64
#define G_  16          // grid cells per dim
#define NCELL_ 4096     // G^3
#define MAXCELLS_ 344   // 7^3 max overlapped cells (+1 slack)
#define SELCAP_ 1024    // inside-list capacity (max expected ~350)

// ---- workspace layout (bytes) ----
#define OFF_FEAT   ((size_t)0)
#define SZ_FEAT    ((size_t)B_*N_*C_*4)                 // 33.5 MB transposed features
#define OFF_COUNTS (OFF_FEAT + SZ_FEAT)
#define OFF_CSTART (OFF_COUNTS + (size_t)B_*NCELL_*4)
#define OFF_CURSOR (OFF_CSTART + (size_t)B_*NCELL_*4)
#define OFF_PLIST4 (OFF_CURSOR + (size_t)B_*NCELL_*4)   // float4 {x,y,z,idx}
#define WS_NEED    (OFF_PLIST4 + (size_t)B_*N_*16)

__device__ __forceinline__ int cell_of(float x, float y, float z) {
    int ix = (int)(x * (float)G_); ix = min(G_ - 1, max(0, ix));
    int iy = (int)(y * (float)G_); iy = min(G_ - 1, max(0, iy));
    int iz = (int)(z * (float)G_); iz = min(G_ - 1, max(0, iz));
    return ix + (iy << 4) + (iz << 8);
}

__global__ __launch_bounds__(256) void zero_k(int* __restrict__ counts) {
    int id = blockIdx.x * 256 + threadIdx.x;
    if (id < B_ * NCELL_) counts[id] = 0;
}

__global__ __launch_bounds__(256) void bin_count_k(const float* __restrict__ key_xyz,
                                                   int* __restrict__ counts) {
    int id = blockIdx.x * 256 + threadIdx.x;   // < B*N
    int b = id >> 14, n = id & (N_ - 1);
    const float* p = key_xyz + ((size_t)b * N_ + n) * 3;
    int cid = cell_of(p[0], p[1], p[2]);
    atomicAdd(&counts[(b << 12) + cid], 1);
}

__global__ __launch_bounds__(1024) void scan_k(const int* __restrict__ counts,
                                               int* __restrict__ cstart,
                                               int* __restrict__ cursor) {
    __shared__ int a[1024];
    int b = blockIdx.x, t = threadIdx.x;
    int base = b << 12;
    int c0 = t * 4;
    int v0 = counts[base + c0 + 0], v1 = counts[base + c0 + 1];
    int v2 = counts[base + c0 + 2], v3 = counts[base + c0 + 3];
    int s = v0 + v1 + v2 + v3;
    a[t] = s;
    __syncthreads();
    for (int o = 1; o < 1024; o <<= 1) {
        int add = (t >= o) ? a[t - o] : 0;
        __syncthreads();
        a[t] += add;
        __syncthreads();
    }
    int excl = a[t] - s;
    int e0 = excl, e1 = e0 + v0, e2 = e1 + v1, e3 = e2 + v2;
    cstart[base + c0 + 0] = e0; cursor[base + c0 + 0] = e0;
    cstart[base + c0 + 1] = e1; cursor[base + c0 + 1] = e1;
    cstart[base + c0 + 2] = e2; cursor[base + c0 + 2] = e2;
    cstart[base + c0 + 3] = e3; cursor[base + c0 + 3] = e3;
}

// ---------------------------------------------------------------------------
// Fused: blocks [0,8192) transpose key_features [B][C][N] -> [B][N][C];
// blocks [8192,8448) scatter points into plist4 {x,y,z,bitcast(idx)}.
// Transpose first: it's the long pole; scatter rides along.
// ---------------------------------------------------------------------------
#define TBLK_ (B_ * (C_/32) * (N_/32))   // 8192
__global__ __launch_bounds__(256) void scatter_transpose_k(
    const float* __restrict__ key_xyz, const float* __restrict__ key_feat,
    int* __restrict__ cursor, float4* __restrict__ plist4,
    float* __restrict__ feat_t)
{
    __shared__ float ttile[32][33];
    int t = threadIdx.x;
    if (blockIdx.x < TBLK_) {
        int id2 = blockIdx.x;
        int b   = id2 >> 11;
        int rem = id2 & 2047;
        int c0  = (rem >> 9) * 32;
        int n0  = (rem & 511) * 32;
        int x = t & 31, y = t >> 5;   // 32 x 8
#pragma unroll
        for (int k = 0; k < 4; ++k)
            ttile[y + 8*k][x] = __builtin_nontemporal_load(
                &key_feat[((size_t)b * C_ + c0 + y + 8*k) * N_ + n0 + x]);
        __syncthreads();
#pragma unroll
        for (int k = 0; k < 4; ++k)
            feat_t[((size_t)b * N_ + n0 + y + 8*k) * C_ + c0 + x] = ttile[x][y + 8*k];
        return;
    }
    int id = (blockIdx.x - TBLK_) * 256 + t;   // < B*N
    int b = id >> 14, n = id & (N_ - 1);
    const float* p = key_xyz + ((size_t)b * N_ + n) * 3;
    float x = p[0], y = p[1], z = p[2];
    int cid = cell_of(x, y, z);
    int pos = atomicAdd(&cursor[(b << 12) + cid], 1);   // batch-local absolute
    plist4[(b << 14) + pos] = make_float4(x, y, z, __int_as_float(n));
}

// ---------------------------------------------------------------------------
// Fused select + gather: one 512-thread block per (b,q), XCD-swizzled so each
// XCD's L2 serves one batch's feat_t slice.
// ---------------------------------------------------------------------------
__global__ __launch_bounds__(512) void selgather_k(
    const float* __restrict__ key_xyz, const float* __restrict__ query,
    const int* __restrict__ counts, const int* __restrict__ cstart,
    const float4* __restrict__ plist4, const float* __restrict__ feat_t,
    float* __restrict__ out_xyz, float* __restrict__ out_feat,
    float* __restrict__ out_mask)
{
    __shared__ int   s_ccnt[MAXCELLS_];
    __shared__ int   s_cstart[MAXCELLS_];
    __shared__ int   s_pref[MAXCELLS_ + 1];
    __shared__ int   s_sel[SELCAP_];
    __shared__ int   s_scnt;
    __shared__ int   s_list[8][NS_];      // radius fallback
    __shared__ int   s_cnt8[8];
    __shared__ int   s_idx[NS_];
    __shared__ int   s_count;
    __shared__ float tile[NS_][65];       // gather staging, conflict-free readout

    // XCD-aware swizzle: block i -> XCD i&7 -> batch (i&7)>>1
    int i    = blockIdx.x;
    int xcd  = i & 7;
    int b    = xcd >> 1;
    int q    = ((i >> 3) << 1) | (xcd & 1);
    int bq   = (b << 10) | q;
    int t    = threadIdx.x;
    int wave = t >> 6, lane = t & 63;

    const float* qp = query + (size_t)bq * 6;
    float cx = qp[0], cy = qp[1], cz = qp[2];
    float hx = 0.5f * qp[3], hy = 0.5f * qp[4], hz = 0.5f * qp[5];
    const float* kb = key_xyz + (size_t)b * N_ * 3;

    if (t == 0) s_scnt = 0;

    // cells overlapping the box, expanded 1 cell (float-boundary safety)
    int ilox = max(0, (int)floorf((cx - hx) * (float)G_) - 1);
    int ihix = min(G_ - 1, (int)floorf((cx + hx) * (float)G_) + 1);
    int iloy = max(0, (int)floorf((cy - hy) * (float)G_) - 1);
    int ihiy = min(G_ - 1, (int)floorf((cy + hy) * (float)G_) + 1);
    int iloz = max(0, (int)floorf((cz - hz) * (float)G_) - 1);
    int ihiz = min(G_ - 1, (int)floorf((cz + hz) * (float)G_) + 1);
    int nx = ihix - ilox + 1, ny = ihiy - iloy + 1, nz = ihiz - iloz + 1;
    int ncells = nx * ny * nz;            // <= 343

    for (int ci = t; ci < ncells; ci += 512) {
        int iz = ci / (nx * ny);
        int r  = ci - iz * (nx * ny);
        int iy = r / nx;
        int ix = r - iy * nx;
        int cid = (ilox + ix) + ((iloy + iy) << 4) + ((iloz + iz) << 8);
        s_ccnt[ci]   = counts[(b << 12) + cid];
        s_cstart[ci] = cstart[(b << 12) + cid];
    }
    __syncthreads();

    if (wave == 0) {                      // exclusive prefix over <=343 counts
        int run = 0;
        for (int base = 0; base < ncells; base += 64) {
            int x = (base + lane < ncells) ? s_ccnt[base + lane] : 0;
            int own = x;
#pragma unroll
            for (int o = 1; o < 64; o <<= 1) {
                int v = __shfl_up(x, (unsigned)o);
                if (lane >= o) x += v;
            }
            if (base + lane < ncells) s_pref[base + lane] = run + x - own;
            run += __shfl(x, 63);
        }
        if (lane == 0) s_pref[ncells] = run;
    }
    __syncthreads();

    int total = s_pref[ncells];
    const float4* pl = plist4 + ((size_t)b << 14);
    for (int ii = t; ii < total; ii += 512) {
        int lo = 0, hi = ncells;
        while (hi - lo > 1) {
            int mid = (lo + hi) >> 1;
            if (s_pref[mid] <= ii) lo = mid; else hi = mid;
        }
        float4 p = pl[s_cstart[lo] + (ii - s_pref[lo])];
        float dx = fabsf(p.x - cx);
        float dy = fabsf(p.y - cy);
        float dz = fabsf(p.z - cz);
        if (dx <= hx && dy <= hy && dz <= hz) {
            int pos = atomicAdd(&s_scnt, 1);
            if (pos < SELCAP_) s_sel[pos] = __float_as_int(p.w);
        }
    }
    __syncthreads();
    int scnt = min(s_scnt, SELCAP_);

    if (scnt > 0) {
        int count = min(scnt, NS_);
        if (scnt <= NS_) {
            // wave-0 shfl bitonic over 64 lanes: no block barriers
            if (wave == 0) {
                int v = (lane < scnt) ? s_sel[lane] : 0x7fffffff;
#pragma unroll
                for (int k = 2; k <= 64; k <<= 1) {
                    for (int j = k >> 1; j > 0; j >>= 1) {
                        int pv = __shfl_xor(v, (unsigned)j);
                        bool dir   = (lane & k) == 0;
                        bool lower = (lane & j) == 0;
                        int mn = min(v, pv), mx = max(v, pv);
                        v = dir ? (lower ? mn : mx) : (lower ? mx : mn);
                    }
                }
                s_idx[lane] = (lane < count) ? v : 0;
                if (lane == 0) s_count = count;
            }
        } else {
            // block bitonic over m = next pow2 >= scnt
            int m = NS_;
            while (m < scnt) m <<= 1;
            for (int ii = t; ii < m; ii += 512)
                if (ii >= scnt) s_sel[ii] = 0x7fffffff;
            __syncthreads();
            for (int k = 2; k <= m; k <<= 1) {
                for (int j = k >> 1; j > 0; j >>= 1) {
                    for (int ii = t; ii < m; ii += 512) {
                        int ixj = ii ^ j;
                        if (ixj > ii) {
                            int va = s_sel[ii], vb = s_sel[ixj];
                            bool up = ((ii & k) == 0);
                            if ((va > vb) == up) { s_sel[ii] = vb; s_sel[ixj] = va; }
                        }
                    }
                    __syncthreads();
                }
            }
            if (t < NS_) s_idx[t] = (t < count) ? s_sel[t] : 0;
            if (t == 0)  s_count = count;
        }
    } else {
        // radius fallback: ordered 8-segment scan (round-2 semantics, 8 waves)
        const float R2 = (float)(0.3 * 0.3);
        const int seg = N_ / 8;           // 2048
        int n0s = wave * seg;
        unsigned long long ltm = (1ull << lane) - 1ull;
        int cnt = 0;
        for (int it = 0; it < seg / 64; ++it) {
            int n = n0s + it * 64 + lane;
            float dx = kb[3*n + 0] - cx;
            float dy = kb[3*n + 1] - cy;
            float dz = kb[3*n + 2] - cz;
            float d2 = dx*dx + dy*dy + dz*dz;   // contract off: matches numpy
            bool r = d2 <= R2;
            unsigned long long mm = __ballot(r);
            if (r) {
                int p = cnt + __popcll(mm & ltm);
                if (p < NS_) s_list[wave][p] = n;
            }
            cnt += __popcll(mm);
            if (cnt >= NS_) break;
        }
        if (lane == 0) s_cnt8[wave] = cnt;
        __syncthreads();
        if (wave == 0) {
            int tot = 0;
#pragma unroll
            for (int w = 0; w < 8; ++w) tot += s_cnt8[w];
            int count = min(tot, NS_);
            int j = lane;
            int idx = 0;
            if (j < count) {
                int w = 0, rem = j;
                while (rem >= s_cnt8[w]) { rem -= s_cnt8[w]; ++w; }  // rem < 64 always
                idx = s_list[w][rem];
            }
            s_idx[j] = idx;
            if (lane == 0) s_count = count;
        }
    }
    __syncthreads();

    // epilogue: mask + centered xyz
    int count = s_count;
    if (t < NS_) {
        int j = t, idx = s_idx[j];
        out_mask[(size_t)bq * NS_ + j] = (j >= count && j > 0) ? 1.0f : 0.0f;
        float px = kb[3*idx + 0] - cx;
        float py = kb[3*idx + 1] - cy;
        float pz = kb[3*idx + 2] - cz;
        size_t xb = ((size_t)b * 3) * NQ_ * NS_ + (size_t)q * NS_ + j;
        out_xyz[xb]                       = px;
        out_xyz[xb +     (size_t)NQ_*NS_] = py;
        out_xyz[xb + 2 * (size_t)NQ_*NS_] = pz;
    }

    // gather: 2 chunks of 64 channels through a 64x65 tile
    const float4* ft4 = (const float4*)feat_t + (size_t)b * N_ * (C_ / 4);
    float* ob = out_feat + (size_t)b * C_ * NQ_ * NS_ + (size_t)q * NS_;
#pragma unroll
    for (int chunk = 0; chunk < 2; ++chunk) {
#pragma unroll
        for (int k = 0; k < 2; ++k) {
            int u  = t + k * 512;         // 0..1023
            int j  = u >> 4;              // row (slot)
            int c4 = u & 15;              // float4 within chunk
            float4 v = ft4[(size_t)s_idx[j] * (C_ / 4) + chunk * 16 + c4];
            tile[j][c4*4 + 0] = v.x;
            tile[j][c4*4 + 1] = v.y;
            tile[j][c4*4 + 2] = v.z;
            tile[j][c4*4 + 3] = v.w;
        }
        __syncthreads();
#pragma unroll
        for (int r = 0; r < 8; ++r) {
            int cl = wave + r * 8;        // chunk-local channel
            __builtin_nontemporal_store(tile[lane][cl],
                &ob[(size_t)(chunk * 64 + cl) * (NQ_ * NS_) + lane]);
        }
        __syncthreads();
    }
}

// ---------------------------------------------------------------------------
// Minimal-workspace fallback (linear select + direct gather).
// ---------------------------------------------------------------------------
__global__ __launch_bounds__(256) void select_lin_k(
    const float* __restrict__ key_xyz, const float* __restrict__ query,
    int* __restrict__ idx_out, float* __restrict__ out_xyz,
    float* __restrict__ out_mask)
{
    int bq = blockIdx.x;
    int b  = bq >> 10;
    int q  = bq & (NQ_ - 1);
    int t    = threadIdx.x;
    int wave = t >> 6;
    int lane = t & 63;

    __shared__ int s_list[4][NS_];
    __shared__ int s_cnt[4];

    const float* qp = query + (size_t)bq * 6;
    float cx = qp[0], cy = qp[1], cz = qp[2];
    float hx = 0.5f * qp[3], hy = 0.5f * qp[4], hz = 0.5f * qp[5];
    const float* kb = key_xyz + (size_t)b * N_ * 3;

    const int seg = N_ / 4;
    int n0 = wave * seg;
    unsigned long long lt = (1ull << lane) - 1ull;

    int cnt = 0;
    for (int it = 0; it < seg / 64; ++it) {
        int n = n0 + it * 64 + lane;
        float dx = fabsf(kb[3*n + 0] - cx);
        float dy = fabsf(kb[3*n + 1] - cy);
        float dz = fabsf(kb[3*n + 2] - cz);
        bool inside = (dx <= hx) && (dy <= hy) && (dz <= hz);
        unsigned long long m = __ballot(inside);
        if (inside) {
            int p = cnt + __popcll(m & lt);
            if (p < NS_) s_list[wave][p] = n;
        }
        cnt += __popcll(m);
        if (cnt >= NS_) break;
    }
    if (lane == 0) s_cnt[wave] = cnt;
    __syncthreads();

    int ti = s_cnt[0] + s_cnt[1] + s_cnt[2] + s_cnt[3];
    if (ti == 0) {
        const float R2 = (float)(0.3 * 0.3);
        cnt = 0;
        for (int it = 0; it < seg / 64; ++it) {
            int n = n0 + it * 64 + lane;
            float dx = kb[3*n + 0] - cx;
            float dy = kb[3*n + 1] - cy;
            float dz = kb[3*n + 2] - cz;
            float d2 = dx*dx + dy*dy + dz*dz;
            bool r = d2 <= R2;
            unsigned long long m = __ballot(r);
            if (r) {
                int p = cnt + __popcll(m & lt);
                if (p < NS_) s_list[wave][p] = n;
            }
            cnt += __popcll(m);
            if (cnt >= NS_) break;
        }
        if (lane == 0) s_cnt[wave] = cnt;
    }
    __syncthreads();

    if (wave == 0) {
        int c0s = min(s_cnt[0], NS_);
        int c1s = min(s_cnt[1], NS_);
        int c2s = min(s_cnt[2], NS_);
        int tot   = s_cnt[0] + s_cnt[1] + s_cnt[2] + s_cnt[3];
        int count = min(tot, NS_);
        int j = lane;
        int idx = 0;
        if (j < count) {
            int o1 = c0s, o2 = o1 + c1s, o3 = o2 + c2s;
            if      (j < o1) idx = s_list[0][j];
            else if (j < o2) idx = s_list[1][j - o1];
            else if (j < o3) idx = s_list[2][j - o2];
            else             idx = s_list[3][j - o3];
        }
        idx_out[(size_t)bq * NS_ + j] = idx;
        out_mask[(size_t)bq * NS_ + j] = (j >= count && j > 0) ? 1.0f : 0.0f;
        float px = kb[3*idx + 0] - cx;
        float py = kb[3*idx + 1] - cy;
        float pz = kb[3*idx + 2] - cz;
        size_t xb = ((size_t)b * 3) * NQ_ * NS_ + (size_t)q * NS_ + j;
        out_xyz[xb]                       = px;
        out_xyz[xb +     (size_t)NQ_*NS_] = py;
        out_xyz[xb + 2 * (size_t)NQ_*NS_] = pz;
    }
}

__global__ __launch_bounds__(256) void gather_direct_k(
    const int* __restrict__ idx_in, const float* __restrict__ key_feat,
    float* __restrict__ out_feat)
{
    int bq = blockIdx.x;
    int b  = bq >> 10;
    int q  = bq & (NQ_ - 1);
    int t    = threadIdx.x;
    int wave = t >> 6;
    int lane = t & 63;
    __shared__ int s_idx[NS_];
    if (t < NS_) s_idx[t] = idx_in[(size_t)bq * NS_ + t];
    __syncthreads();
    const float* fb = key_feat + (size_t)b * C_ * N_;
    float* ob = out_feat + (size_t)b * C_ * NQ_ * NS_ + (size_t)q * NS_;
    int idx = s_idx[lane];
    for (int c = wave; c < C_; c += 4)
        ob[(size_t)c * NQ_ * NS_ + lane] = fb[(size_t)c * N_ + idx];
}

extern "C" void kernel_launch(void* const* d_in, const int* in_sizes, int n_in,
                              void* d_out, int out_size, void* d_ws, size_t ws_size,
                              hipStream_t stream) {
    const float* key_xyz  = (const float*)d_in[0];
    const float* key_feat = (const float*)d_in[1];
    const float* query    = (const float*)d_in[2];

    float* out      = (float*)d_out;
    float* out_xyz  = out;
    float* out_feat = out + (size_t)B_ * 3 * NQ_ * NS_;
    float* out_mask = out_feat + (size_t)B_ * C_ * NQ_ * NS_;

    char* ws = (char*)d_ws;
    float*  ft      = (float*)(ws + OFF_FEAT);
    int*    counts  = (int*)(ws + OFF_COUNTS);
    int*    cstartp = (int*)(ws + OFF_CSTART);
    int*    cursor  = (int*)(ws + OFF_CURSOR);
    float4* plist4  = (float4*)(ws + OFF_PLIST4);

    if (ws_size >= WS_NEED) {
        zero_k<<<dim3((B_ * NCELL_ + 255) / 256), dim3(256), 0, stream>>>(counts);
        bin_count_k<<<dim3(B_ * N_ / 256), dim3(256), 0, stream>>>(key_xyz, counts);
        scan_k<<<dim3(B_), dim3(1024), 0, stream>>>(counts, cstartp, cursor);
        scatter_transpose_k<<<dim3(TBLK_ + B_ * N_ / 256), dim3(256), 0, stream>>>(
            key_xyz, key_feat, cursor, plist4, ft);
        selgather_k<<<dim3(B_ * NQ_), dim3(512), 0, stream>>>(
            key_xyz, query, counts, cstartp, plist4, ft,
            out_xyz, out_feat, out_mask);
    } else {
        int* d_idx = (int*)d_ws;
        select_lin_k<<<dim3(B_ * NQ_), dim3(256), 0, stream>>>(
            key_xyz, query, d_idx, out_xyz, out_mask);
        gather_direct_k<<<dim3(B_ * NQ_), dim3(256), 0, stream>>>(
            d_idx, key_feat, out_feat);
    }
}

// Round 6
// 203.559 us; speedup vs baseline: 1.4925x; 1.0367x over previous
//
#include <hip/hip_runtime.h>

#pragma clang fp contract(off)

#define B_  4
#define N_  16384
#define NQ_ 1024
#define C_  128
#define NS_ 64
#define G_  16          // grid cells per dim
#define NCELL_ 4096     // G^3
#define MAXCELLS_ 344   // 7^3 max overlapped cells (+1 slack)
#define SELCAP_ 1024    // inside-list capacity (max expected ~350)

// ---- workspace layout (bytes) ----
#define OFF_FEAT   ((size_t)0)
#define SZ_FEAT    ((size_t)B_*N_*C_*4)                 // 33.5 MB transposed features
#define OFF_COUNTS (OFF_FEAT + SZ_FEAT)
#define OFF_CURSOR (OFF_COUNTS + (size_t)B_*NCELL_*4)
#define OFF_CINFO  (OFF_CURSOR + (size_t)B_*NCELL_*4)   // int2 {count,start}
#define OFF_PLIST4 (OFF_CINFO + (size_t)B_*NCELL_*8)    // float4 {x,y,z,idx}
#define WS_NEED    (OFF_PLIST4 + (size_t)B_*N_*16)

__device__ __forceinline__ int cell_of(float x, float y, float z) {
    int ix = (int)(x * (float)G_); ix = min(G_ - 1, max(0, ix));
    int iy = (int)(y * (float)G_); iy = min(G_ - 1, max(0, iy));
    int iz = (int)(z * (float)G_); iz = min(G_ - 1, max(0, iz));
    return ix + (iy << 4) + (iz << 8);
}

__global__ __launch_bounds__(256) void bin_count_k(const float* __restrict__ key_xyz,
                                                   int* __restrict__ counts) {
    int id = blockIdx.x * 256 + threadIdx.x;   // < B*N
    int b = id >> 14, n = id & (N_ - 1);
    const float* p = key_xyz + ((size_t)b * N_ + n) * 3;
    int cid = cell_of(p[0], p[1], p[2]);
    atomicAdd(&counts[(b << 12) + cid], 1);
}

// wave-shfl scan: 2 barriers (was 20)
__global__ __launch_bounds__(1024) void scan_k(const int* __restrict__ counts,
                                               int2* __restrict__ cinfo,
                                               int* __restrict__ cursor) {
    __shared__ int wsum[16];
    int b = blockIdx.x, t = threadIdx.x;
    int wave = t >> 6, lane = t & 63;
    int base = b << 12;
    int c0 = t << 2;
    int v0 = counts[base + c0 + 0], v1 = counts[base + c0 + 1];
    int v2 = counts[base + c0 + 2], v3 = counts[base + c0 + 3];
    int s = v0 + v1 + v2 + v3;
    int x = s;
#pragma unroll
    for (int o = 1; o < 64; o <<= 1) {
        int v = __shfl_up(x, (unsigned)o);
        if (lane >= o) x += v;
    }
    if (lane == 63) wsum[wave] = x;
    __syncthreads();
    if (t < 16) {
        int y = wsum[t];
#pragma unroll
        for (int o = 1; o < 16; o <<= 1) {
            int v = __shfl_up(y, (unsigned)o);
            if (t >= o) y += v;
        }
        wsum[t] = y;
    }
    __syncthreads();
    int off = (wave ? wsum[wave - 1] : 0) + x - s;   // exclusive prefix
    int e0 = off, e1 = e0 + v0, e2 = e1 + v1, e3 = e2 + v2;
    cinfo[base + c0 + 0] = make_int2(v0, e0); cursor[base + c0 + 0] = e0;
    cinfo[base + c0 + 1] = make_int2(v1, e1); cursor[base + c0 + 1] = e1;
    cinfo[base + c0 + 2] = make_int2(v2, e2); cursor[base + c0 + 2] = e2;
    cinfo[base + c0 + 3] = make_int2(v3, e3); cursor[base + c0 + 3] = e3;
}

// ---------------------------------------------------------------------------
// Fused: blocks [0,8192) transpose key_features [B][C][N] -> [B][N][C];
// blocks [8192,8448) scatter points into plist4 {x,y,z,bitcast(idx)}.
// ---------------------------------------------------------------------------
#define TBLK_ (B_ * (C_/32) * (N_/32))   // 8192
__global__ __launch_bounds__(256) void scatter_transpose_k(
    const float* __restrict__ key_xyz, const float* __restrict__ key_feat,
    int* __restrict__ cursor, float4* __restrict__ plist4,
    float* __restrict__ feat_t)
{
    __shared__ float ttile[32][33];
    int t = threadIdx.x;
    if (blockIdx.x < TBLK_) {
        int id2 = blockIdx.x;
        int b   = id2 >> 11;
        int rem = id2 & 2047;
        int c0  = (rem >> 9) * 32;
        int n0  = (rem & 511) * 32;
        int x = t & 31, y = t >> 5;   // 32 x 8
#pragma unroll
        for (int k = 0; k < 4; ++k)
            ttile[y + 8*k][x] = __builtin_nontemporal_load(
                &key_feat[((size_t)b * C_ + c0 + y + 8*k) * N_ + n0 + x]);
        __syncthreads();
#pragma unroll
        for (int k = 0; k < 4; ++k)
            feat_t[((size_t)b * N_ + n0 + y + 8*k) * C_ + c0 + x] = ttile[x][y + 8*k];
        return;
    }
    int id = (blockIdx.x - TBLK_) * 256 + t;   // < B*N
    int b = id >> 14, n = id & (N_ - 1);
    const float* p = key_xyz + ((size_t)b * N_ + n) * 3;
    float x = p[0], y = p[1], z = p[2];
    int cid = cell_of(x, y, z);
    int pos = atomicAdd(&cursor[(b << 12) + cid], 1);   // batch-local absolute
    plist4[(b << 14) + pos] = make_float4(x, y, z, __int_as_float(n));
}

// ---------------------------------------------------------------------------
// Fused select + gather: one 512-thread block per (b,q), XCD-swizzled.
// Sort strategy: scnt<=64 -> single-wave shfl bitonic (0 barriers);
// 64<scnt<=512 -> 8 per-wave shfl bitonics + rank-merge (2 barriers);
// scnt>512 (never expected) -> block bitonic fallback.
// ---------------------------------------------------------------------------
__global__ __launch_bounds__(512) void selgather_k(
    const float* __restrict__ key_xyz, const float* __restrict__ query,
    const int2* __restrict__ cinfo, const float4* __restrict__ plist4,
    const float* __restrict__ feat_t,
    float* __restrict__ out_xyz, float* __restrict__ out_feat,
    float* __restrict__ out_mask)
{
    __shared__ int   s_ccnt[MAXCELLS_];
    __shared__ int   s_cstart[MAXCELLS_];
    __shared__ int   s_pref[MAXCELLS_ + 1];
    __shared__ int   s_sel[SELCAP_];
    __shared__ int   s_scnt;
    __shared__ int   s_list[8][NS_];      // radius fallback
    __shared__ int   s_cnt8[8];
    __shared__ int   s_idx[NS_];
    __shared__ int   s_count;
    __shared__ float tile[NS_][65];       // gather staging, conflict-free readout

    // XCD-aware swizzle: block i -> XCD i&7 -> batch (i&7)>>1
    int i    = blockIdx.x;
    int xcd  = i & 7;
    int b    = xcd >> 1;
    int q    = ((i >> 3) << 1) | (xcd & 1);
    int bq   = (b << 10) | q;
    int t    = threadIdx.x;
    int wave = t >> 6, lane = t & 63;

    const float* qp = query + (size_t)bq * 6;
    float cx = qp[0], cy = qp[1], cz = qp[2];
    float hx = 0.5f * qp[3], hy = 0.5f * qp[4], hz = 0.5f * qp[5];
    const float* kb = key_xyz + (size_t)b * N_ * 3;

    if (t == 0) s_scnt = 0;

    // cells overlapping the box, expanded 1 cell (float-boundary safety)
    int ilox = max(0, (int)floorf((cx - hx) * (float)G_) - 1);
    int ihix = min(G_ - 1, (int)floorf((cx + hx) * (float)G_) + 1);
    int iloy = max(0, (int)floorf((cy - hy) * (float)G_) - 1);
    int ihiy = min(G_ - 1, (int)floorf((cy + hy) * (float)G_) + 1);
    int iloz = max(0, (int)floorf((cz - hz) * (float)G_) - 1);
    int ihiz = min(G_ - 1, (int)floorf((cz + hz) * (float)G_) + 1);
    int nx = ihix - ilox + 1, ny = ihiy - iloy + 1, nz = ihiz - iloz + 1;
    int ncells = nx * ny * nz;            // <= 343

    const int2* ci = cinfo + (b << 12);
    for (int cc = t; cc < ncells; cc += 512) {
        int iz = cc / (nx * ny);
        int r  = cc - iz * (nx * ny);
        int iy = r / nx;
        int ix = r - iy * nx;
        int cid = (ilox + ix) + ((iloy + iy) << 4) + ((iloz + iz) << 8);
        int2 v = ci[cid];
        s_ccnt[cc]   = v.x;
        s_cstart[cc] = v.y;
    }
    __syncthreads();

    if (wave == 0) {                      // exclusive prefix over <=343 counts
        int run = 0;
        for (int base = 0; base < ncells; base += 64) {
            int x = (base + lane < ncells) ? s_ccnt[base + lane] : 0;
            int own = x;
#pragma unroll
            for (int o = 1; o < 64; o <<= 1) {
                int v = __shfl_up(x, (unsigned)o);
                if (lane >= o) x += v;
            }
            if (base + lane < ncells) s_pref[base + lane] = run + x - own;
            run += __shfl(x, 63);
        }
        if (lane == 0) s_pref[ncells] = run;
    }
    __syncthreads();

    int total = s_pref[ncells];
    const float4* pl = plist4 + ((size_t)b << 14);
    for (int ii = t; ii < total; ii += 512) {
        int lo = 0, hi = ncells;
        while (hi - lo > 1) {
            int mid = (lo + hi) >> 1;
            if (s_pref[mid] <= ii) lo = mid; else hi = mid;
        }
        float4 p = pl[s_cstart[lo] + (ii - s_pref[lo])];
        float dx = fabsf(p.x - cx);
        float dy = fabsf(p.y - cy);
        float dz = fabsf(p.z - cz);
        if (dx <= hx && dy <= hy && dz <= hz) {
            int pos = atomicAdd(&s_scnt, 1);
            if (pos < SELCAP_) s_sel[pos] = __float_as_int(p.w);
        }
    }
    __syncthreads();
    int scnt = min(s_scnt, SELCAP_);

    if (scnt > 0) {
        int count = min(scnt, NS_);
        if (scnt <= NS_) {
            // wave-0 shfl bitonic over 64 lanes: no block barriers
            if (wave == 0) {
                int v = (lane < scnt) ? s_sel[lane] : 0x7fffffff;
#pragma unroll
                for (int k = 2; k <= 64; k <<= 1) {
                    for (int j = k >> 1; j > 0; j >>= 1) {
                        int pv = __shfl_xor(v, (unsigned)j);
                        bool dir   = (lane & k) == 0;
                        bool lower = (lane & j) == 0;
                        int mn = min(v, pv), mx = max(v, pv);
                        v = dir ? (lower ? mn : mx) : (lower ? mx : mn);
                    }
                }
                s_idx[lane] = (lane < count) ? v : 0;
                if (lane == 0) s_count = count;
            }
        } else if (scnt <= 512) {
            // 8 per-wave sorts (0 barriers each) + rank-merge (2 barriers)
            int nw = (scnt + 63) >> 6;
            int base = wave << 6;
            int v = (base + lane < scnt) ? s_sel[base + lane] : 0x7fffffff;
#pragma unroll
            for (int k = 2; k <= 64; k <<= 1) {
                for (int j = k >> 1; j > 0; j >>= 1) {
                    int pv = __shfl_xor(v, (unsigned)j);
                    bool dir   = (lane & k) == 0;
                    bool lower = (lane & j) == 0;
                    int mn = min(v, pv), mx = max(v, pv);
                    v = dir ? (lower ? mn : mx) : (lower ? mx : mn);
                }
            }
            s_sel[base + lane] = v;       // sorted slice, distinct values
            __syncthreads();
            int e = s_sel[t];
            if (t < (nw << 6) && e != 0x7fffffff) {
                int r = lane;             // rank within own sorted slice
#pragma unroll
                for (int w = 0; w < 8; ++w) {
                    if (w == wave || w >= nw) continue;
                    int bw = w << 6;
                    int pos = 0;
#pragma unroll
                    for (int s2 = 32; s2 >= 1; s2 >>= 1)
                        if (s_sel[bw + pos + s2 - 1] < e) pos += s2;
                    if (s_sel[bw + pos] < e) ++pos;   // pos in [0,64]
                    r += pos;
                }
                if (r < NS_) s_idx[r] = e;   // ranks 0..count-1 fully cover
            }
            if (t == 0) s_count = NS_;        // count == 64 here
        } else {
            // block bitonic over m = next pow2 >= scnt (safety net)
            int m = NS_;
            while (m < scnt) m <<= 1;
            for (int ii = t; ii < m; ii += 512)
                if (ii >= scnt) s_sel[ii] = 0x7fffffff;
            __syncthreads();
            for (int k = 2; k <= m; k <<= 1) {
                for (int j = k >> 1; j > 0; j >>= 1) {
                    for (int ii = t; ii < m; ii += 512) {
                        int ixj = ii ^ j;
                        if (ixj > ii) {
                            int va = s_sel[ii], vb = s_sel[ixj];
                            bool up = ((ii & k) == 0);
                            if ((va > vb) == up) { s_sel[ii] = vb; s_sel[ixj] = va; }
                        }
                    }
                    __syncthreads();
                }
            }
            if (t < NS_) s_idx[t] = (t < count) ? s_sel[t] : 0;
            if (t == 0)  s_count = count;
        }
    } else {
        // radius fallback: ordered 8-segment scan (early exit ~9 iters at
        // ball density 0.11)
        const float R2 = (float)(0.3 * 0.3);
        const int seg = N_ / 8;           // 2048
        int n0s = wave * seg;
        unsigned long long ltm = (1ull << lane) - 1ull;
        int cnt = 0;
        for (int it = 0; it < seg / 64; ++it) {
            int n = n0s + it * 64 + lane;
            float dx = kb[3*n + 0] - cx;
            float dy = kb[3*n + 1] - cy;
            float dz = kb[3*n + 2] - cz;
            float d2 = dx*dx + dy*dy + dz*dz;   // contract off: matches numpy
            bool r = d2 <= R2;
            unsigned long long mm = __ballot(r);
            if (r) {
                int p = cnt + __popcll(mm & ltm);
                if (p < NS_) s_list[wave][p] = n;
            }
            cnt += __popcll(mm);
            if (cnt >= NS_) break;
        }
        if (lane == 0) s_cnt8[wave] = cnt;
        __syncthreads();
        if (wave == 0) {
            int tot = 0;
#pragma unroll
            for (int w = 0; w < 8; ++w) tot += s_cnt8[w];
            int count = min(tot, NS_);
            int j = lane;
            int idx = 0;
            if (j < count) {
                int w = 0, rem = j;
                while (rem >= s_cnt8[w]) { rem -= s_cnt8[w]; ++w; }
                idx = s_list[w][rem];
            }
            s_idx[j] = idx;
            if (lane == 0) s_count = count;
        }
    }
    __syncthreads();

    // epilogue: mask + centered xyz
    int count = s_count;
    if (t < NS_) {
        int j = t, idx = s_idx[j];
        out_mask[(size_t)bq * NS_ + j] = (j >= count && j > 0) ? 1.0f : 0.0f;
        float px = kb[3*idx + 0] - cx;
        float py = kb[3*idx + 1] - cy;
        float pz = kb[3*idx + 2] - cz;
        size_t xb = ((size_t)b * 3) * NQ_ * NS_ + (size_t)q * NS_ + j;
        out_xyz[xb]                       = px;
        out_xyz[xb +     (size_t)NQ_*NS_] = py;
        out_xyz[xb + 2 * (size_t)NQ_*NS_] = pz;
    }

    // gather: 2 chunks of 64 channels through a 64x65 tile
    const float4* ft4 = (const float4*)feat_t + (size_t)b * N_ * (C_ / 4);
    float* ob = out_feat + (size_t)b * C_ * NQ_ * NS_ + (size_t)q * NS_;
#pragma unroll
    for (int chunk = 0; chunk < 2; ++chunk) {
#pragma unroll
        for (int k = 0; k < 2; ++k) {
            int u  = t + k * 512;         // 0..1023
            int j  = u >> 4;              // row (slot)
            int c4 = u & 15;              // float4 within chunk
            float4 v = ft4[(size_t)s_idx[j] * (C_ / 4) + chunk * 16 + c4];
            tile[j][c4*4 + 0] = v.x;
            tile[j][c4*4 + 1] = v.y;
            tile[j][c4*4 + 2] = v.z;
            tile[j][c4*4 + 3] = v.w;
        }
        __syncthreads();
#pragma unroll
        for (int r = 0; r < 8; ++r) {
            int cl = wave + r * 8;        // chunk-local channel
            __builtin_nontemporal_store(tile[lane][cl],
                &ob[(size_t)(chunk * 64 + cl) * (NQ_ * NS_) + lane]);
        }
        __syncthreads();
    }
}

// ---------------------------------------------------------------------------
// Minimal-workspace fallback (linear select + direct gather).
// ---------------------------------------------------------------------------
__global__ __launch_bounds__(256) void select_lin_k(
    const float* __restrict__ key_xyz, const float* __restrict__ query,
    int* __restrict__ idx_out, float* __restrict__ out_xyz,
    float* __restrict__ out_mask)
{
    int bq = blockIdx.x;
    int b  = bq >> 10;
    int q  = bq & (NQ_ - 1);
    int t    = threadIdx.x;
    int wave = t >> 6;
    int lane = t & 63;

    __shared__ int s_list[4][NS_];
    __shared__ int s_cnt[4];

    const float* qp = query + (size_t)bq * 6;
    float cx = qp[0], cy = qp[1], cz = qp[2];
    float hx = 0.5f * qp[3], hy = 0.5f * qp[4], hz = 0.5f * qp[5];
    const float* kb = key_xyz + (size_t)b * N_ * 3;

    const int seg = N_ / 4;
    int n0 = wave * seg;
    unsigned long long lt = (1ull << lane) - 1ull;

    int cnt = 0;
    for (int it = 0; it < seg / 64; ++it) {
        int n = n0 + it * 64 + lane;
        float dx = fabsf(kb[3*n + 0] - cx);
        float dy = fabsf(kb[3*n + 1] - cy);
        float dz = fabsf(kb[3*n + 2] - cz);
        bool inside = (dx <= hx) && (dy <= hy) && (dz <= hz);
        unsigned long long m = __ballot(inside);
        if (inside) {
            int p = cnt + __popcll(m & lt);
            if (p < NS_) s_list[wave][p] = n;
        }
        cnt += __popcll(m);
        if (cnt >= NS_) break;
    }
    if (lane == 0) s_cnt[wave] = cnt;
    __syncthreads();

    int ti = s_cnt[0] + s_cnt[1] + s_cnt[2] + s_cnt[3];
    if (ti == 0) {
        const float R2 = (float)(0.3 * 0.3);
        cnt = 0;
        for (int it = 0; it < seg / 64; ++it) {
            int n = n0 + it * 64 + lane;
            float dx = kb[3*n + 0] - cx;
            float dy = kb[3*n + 1] - cy;
            float dz = kb[3*n + 2] - cz;
            float d2 = dx*dx + dy*dy + dz*dz;
            bool r = d2 <= R2;
            unsigned long long m = __ballot(r);
            if (r) {
                int p = cnt + __popcll(m & lt);
                if (p < NS_) s_list[wave][p] = n;
            }
            cnt += __popcll(m);
            if (cnt >= NS_) break;
        }
        if (lane == 0) s_cnt[wave] = cnt;
    }
    __syncthreads();

    if (wave == 0) {
        int c0s = min(s_cnt[0], NS_);
        int c1s = min(s_cnt[1], NS_);
        int c2s = min(s_cnt[2], NS_);
        int tot   = s_cnt[0] + s_cnt[1] + s_cnt[2] + s_cnt[3];
        int count = min(tot, NS_);
        int j = lane;
        int idx = 0;
        if (j < count) {
            int o1 = c0s, o2 = o1 + c1s, o3 = o2 + c2s;
            if      (j < o1) idx = s_list[0][j];
            else if (j < o2) idx = s_list[1][j - o1];
            else if (j < o3) idx = s_list[2][j - o2];
            else             idx = s_list[3][j - o3];
        }
        idx_out[(size_t)bq * NS_ + j] = idx;
        out_mask[(size_t)bq * NS_ + j] = (j >= count && j > 0) ? 1.0f : 0.0f;
        float px = kb[3*idx + 0] - cx;
        float py = kb[3*idx + 1] - cy;
        float pz = kb[3*idx + 2] - cz;
        size_t xb = ((size_t)b * 3) * NQ_ * NS_ + (size_t)q * NS_ + j;
        out_xyz[xb]                       = px;
        out_xyz[xb +     (size_t)NQ_*NS_] = py;
        out_xyz[xb + 2 * (size_t)NQ_*NS_] = pz;
    }
}

__global__ __launch_bounds__(256) void gather_direct_k(
    const int* __restrict__ idx_in, const float* __restrict__ key_feat,
    float* __restrict__ out_feat)
{
    int bq = blockIdx.x;
    int b  = bq >> 10;
    int q  = bq & (NQ_ - 1);
    int t    = threadIdx.x;
    int wave = t >> 6;
    int lane = t & 63;
    __shared__ int s_idx[NS_];
    if (t < NS_) s_idx[t] = idx_in[(size_t)bq * NS_ + t];
    __syncthreads();
    const float* fb = key_feat + (size_t)b * C_ * N_;
    float* ob = out_feat + (size_t)b * C_ * NQ_ * NS_ + (size_t)q * NS_;
    int idx = s_idx[lane];
    for (int c = wave; c < C_; c += 4)
        ob[(size_t)c * NQ_ * NS_ + lane] = fb[(size_t)c * N_ + idx];
}

extern "C" void kernel_launch(void* const* d_in, const int* in_sizes, int n_in,
                              void* d_out, int out_size, void* d_ws, size_t ws_size,
                              hipStream_t stream) {
    const float* key_xyz  = (const float*)d_in[0];
    const float* key_feat = (const float*)d_in[1];
    const float* query    = (const float*)d_in[2];

    float* out      = (float*)d_out;
    float* out_xyz  = out;
    float* out_feat = out + (size_t)B_ * 3 * NQ_ * NS_;
    float* out_mask = out_feat + (size_t)B_ * C_ * NQ_ * NS_;

    char* ws = (char*)d_ws;
    float*  ft      = (float*)(ws + OFF_FEAT);
    int*    counts  = (int*)(ws + OFF_COUNTS);
    int*    cursor  = (int*)(ws + OFF_CURSOR);
    int2*   cinfo   = (int2*)(ws + OFF_CINFO);
    float4* plist4  = (float4*)(ws + OFF_PLIST4);

    if (ws_size >= WS_NEED) {
        hipMemsetAsync(counts, 0, (size_t)B_ * NCELL_ * 4, stream);
        bin_count_k<<<dim3(B_ * N_ / 256), dim3(256), 0, stream>>>(key_xyz, counts);
        scan_k<<<dim3(B_), dim3(1024), 0, stream>>>(counts, cinfo, cursor);
        scatter_transpose_k<<<dim3(TBLK_ + B_ * N_ / 256), dim3(256), 0, stream>>>(
            key_xyz, key_feat, cursor, plist4, ft);
        selgather_k<<<dim3(B_ * NQ_), dim3(512), 0, stream>>>(
            key_xyz, query, cinfo, plist4, ft, out_xyz, out_feat, out_mask);
    } else {
        int* d_idx = (int*)d_ws;
        select_lin_k<<<dim3(B_ * NQ_), dim3(256), 0, stream>>>(
            key_xyz, query, d_idx, out_xyz, out_mask);
        gather_direct_k<<<dim3(B_ * NQ_), dim3(256), 0, stream>>>(
            d_idx, key_feat, out_feat);
    }
}

// Round 7
// 199.315 us; speedup vs baseline: 1.5242x; 1.0213x over previous
//
#include <hip/hip_runtime.h>

#pragma clang fp contract(off)

#define B_  4
#define N_  16384
#define NQ_ 1024
#define C_  128
#define NS_ 64
#define G_  16          // grid cells per dim
#define NCELL_ 4096     // G^3
#define MAXCELLS_ 224   // tight bounds: hx<=0.125 -> <=6 cells/dim -> <=216
#define SELCAP_ 1024    // inside-list capacity (max expected ~350)

// ---- workspace layout (bytes) ----
#define OFF_FEAT   ((size_t)0)
#define SZ_FEAT    ((size_t)B_*N_*C_*4)                 // 33.5 MB transposed features
#define OFF_COUNTS (OFF_FEAT + SZ_FEAT)
#define OFF_CURSOR (OFF_COUNTS + (size_t)B_*NCELL_*4)
#define OFF_CINFO  (OFF_CURSOR + (size_t)B_*NCELL_*4)   // int2 {count,start}
#define OFF_PLIST4 (OFF_CINFO + (size_t)B_*NCELL_*8)    // float4 {x,y,z,idx}
#define WS_NEED    (OFF_PLIST4 + (size_t)B_*N_*16)

__device__ __forceinline__ int cell_of(float x, float y, float z) {
    int ix = (int)(x * (float)G_); ix = min(G_ - 1, max(0, ix));
    int iy = (int)(y * (float)G_); iy = min(G_ - 1, max(0, iy));
    int iz = (int)(z * (float)G_); iz = min(G_ - 1, max(0, iz));
    return ix + (iy << 4) + (iz << 8);
}

// epsilon-safe cell range for interval [c-h, c+h]:
// x*16 is EXACT (pow2 mul); the inside test |fl(x-c)|<=h and lo/hi=fl(c∓h)
// carry <=2 roundings => 3e-7 relative (+1e-9 abs) strictly covers them.
__device__ __forceinline__ int cell_lo(float c, float h) {
    float lo = c - h;
    lo -= fabsf(lo) * 3e-7f + 1e-9f;
    return max(0, (int)floorf(lo * (float)G_));
}
__device__ __forceinline__ int cell_hi(float c, float h) {
    float hi = c + h;
    hi += fabsf(hi) * 3e-7f + 1e-9f;
    return min(G_ - 1, (int)floorf(hi * (float)G_));
}

__global__ __launch_bounds__(256) void bin_count_k(const float* __restrict__ key_xyz,
                                                   int* __restrict__ counts) {
    int id = blockIdx.x * 256 + threadIdx.x;   // < B*N
    int b = id >> 14, n = id & (N_ - 1);
    const float* p = key_xyz + ((size_t)b * N_ + n) * 3;
    int cid = cell_of(p[0], p[1], p[2]);
    atomicAdd(&counts[(b << 12) + cid], 1);
}

// wave-shfl scan: 2 barriers
__global__ __launch_bounds__(1024) void scan_k(const int* __restrict__ counts,
                                               int2* __restrict__ cinfo,
                                               int* __restrict__ cursor) {
    __shared__ int wsum[16];
    int b = blockIdx.x, t = threadIdx.x;
    int wave = t >> 6, lane = t & 63;
    int base = b << 12;
    int c0 = t << 2;
    int v0 = counts[base + c0 + 0], v1 = counts[base + c0 + 1];
    int v2 = counts[base + c0 + 2], v3 = counts[base + c0 + 3];
    int s = v0 + v1 + v2 + v3;
    int x = s;
#pragma unroll
    for (int o = 1; o < 64; o <<= 1) {
        int v = __shfl_up(x, (unsigned)o);
        if (lane >= o) x += v;
    }
    if (lane == 63) wsum[wave] = x;
    __syncthreads();
    if (t < 16) {
        int y = wsum[t];
#pragma unroll
        for (int o = 1; o < 16; o <<= 1) {
            int v = __shfl_up(y, (unsigned)o);
            if (t >= o) y += v;
        }
        wsum[t] = y;
    }
    __syncthreads();
    int off = (wave ? wsum[wave - 1] : 0) + x - s;   // exclusive prefix
    int e0 = off, e1 = e0 + v0, e2 = e1 + v1, e3 = e2 + v2;
    cinfo[base + c0 + 0] = make_int2(v0, e0); cursor[base + c0 + 0] = e0;
    cinfo[base + c0 + 1] = make_int2(v1, e1); cursor[base + c0 + 1] = e1;
    cinfo[base + c0 + 2] = make_int2(v2, e2); cursor[base + c0 + 2] = e2;
    cinfo[base + c0 + 3] = make_int2(v3, e3); cursor[base + c0 + 3] = e3;
}

// ---------------------------------------------------------------------------
// Fused: blocks [0,8192) transpose key_features [B][C][N] -> [B][N][C];
// blocks [8192,8448) scatter points into plist4 {x,y,z,bitcast(idx)}.
// ---------------------------------------------------------------------------
#define TBLK_ (B_ * (C_/32) * (N_/32))   // 8192
__global__ __launch_bounds__(256) void scatter_transpose_k(
    const float* __restrict__ key_xyz, const float* __restrict__ key_feat,
    int* __restrict__ cursor, float4* __restrict__ plist4,
    float* __restrict__ feat_t)
{
    __shared__ float ttile[32][33];
    int t = threadIdx.x;
    if (blockIdx.x < TBLK_) {
        int id2 = blockIdx.x;
        int b   = id2 >> 11;
        int rem = id2 & 2047;
        int c0  = (rem >> 9) * 32;
        int n0  = (rem & 511) * 32;
        int x = t & 31, y = t >> 5;   // 32 x 8
#pragma unroll
        for (int k = 0; k < 4; ++k)
            ttile[y + 8*k][x] = __builtin_nontemporal_load(
                &key_feat[((size_t)b * C_ + c0 + y + 8*k) * N_ + n0 + x]);
        __syncthreads();
#pragma unroll
        for (int k = 0; k < 4; ++k)
            feat_t[((size_t)b * N_ + n0 + y + 8*k) * C_ + c0 + x] = ttile[x][y + 8*k];
        return;
    }
    int id = (blockIdx.x - TBLK_) * 256 + t;   // < B*N
    int b = id >> 14, n = id & (N_ - 1);
    const float* p = key_xyz + ((size_t)b * N_ + n) * 3;
    float x = p[0], y = p[1], z = p[2];
    int cid = cell_of(x, y, z);
    int pos = atomicAdd(&cursor[(b << 12) + cid], 1);   // batch-local absolute
    plist4[(b << 14) + pos] = make_float4(x, y, z, __int_as_float(n));
}

// ---------------------------------------------------------------------------
// Fused select + gather: one 512-thread block per (b,q), XCD-swizzled.
// Tight (epsilon-safe) cell window: ~160 candidates/query (was ~630).
// Sort strategy: scnt<=64 -> single-wave shfl bitonic (0 barriers);
// 64<scnt<=512 -> 8 per-wave shfl bitonics + rank-merge (2 barriers);
// scnt>512 (never expected) -> block bitonic fallback.
// ---------------------------------------------------------------------------
__global__ __launch_bounds__(512) void selgather_k(
    const float* __restrict__ key_xyz, const float* __restrict__ query,
    const int2* __restrict__ cinfo, const float4* __restrict__ plist4,
    const float* __restrict__ feat_t,
    float* __restrict__ out_xyz, float* __restrict__ out_feat,
    float* __restrict__ out_mask)
{
    __shared__ int   s_ccnt[MAXCELLS_];
    __shared__ int   s_cstart[MAXCELLS_];
    __shared__ int   s_pref[MAXCELLS_ + 1];
    __shared__ int   s_sel[SELCAP_];
    __shared__ int   s_scnt;
    __shared__ int   s_list[8][NS_];      // radius fallback
    __shared__ int   s_cnt8[8];
    __shared__ int   s_idx[NS_];
    __shared__ int   s_count;
    __shared__ float tile[NS_][65];       // gather staging, conflict-free readout

    // XCD-aware swizzle: block i -> XCD i&7 -> batch (i&7)>>1
    int i    = blockIdx.x;
    int xcd  = i & 7;
    int b    = xcd >> 1;
    int q    = ((i >> 3) << 1) | (xcd & 1);
    int bq   = (b << 10) | q;
    int t    = threadIdx.x;
    int wave = t >> 6, lane = t & 63;

    const float* qp = query + (size_t)bq * 6;
    float cx = qp[0], cy = qp[1], cz = qp[2];
    float hx = 0.5f * qp[3], hy = 0.5f * qp[4], hz = 0.5f * qp[5];
    const float* kb = key_xyz + (size_t)b * N_ * 3;

    if (t == 0) s_scnt = 0;

    // tight epsilon-safe cell window (no ±1 expansion)
    int ilox = cell_lo(cx, hx), ihix = cell_hi(cx, hx);
    int iloy = cell_lo(cy, hy), ihiy = cell_hi(cy, hy);
    int iloz = cell_lo(cz, hz), ihiz = cell_hi(cz, hz);
    int nx = ihix - ilox + 1, ny = ihiy - iloy + 1, nz = ihiz - iloz + 1;
    int ncells = nx * ny * nz;            // <= 216

    const int2* ci = cinfo + (b << 12);
    for (int cc = t; cc < ncells; cc += 512) {
        int iz = cc / (nx * ny);
        int r  = cc - iz * (nx * ny);
        int iy = r / nx;
        int ix = r - iy * nx;
        int cid = (ilox + ix) + ((iloy + iy) << 4) + ((iloz + iz) << 8);
        int2 v = ci[cid];
        s_ccnt[cc]   = v.x;
        s_cstart[cc] = v.y;
    }
    __syncthreads();

    if (wave == 0) {                      // exclusive prefix over <=216 counts
        int run = 0;
        for (int base = 0; base < ncells; base += 64) {
            int x = (base + lane < ncells) ? s_ccnt[base + lane] : 0;
            int own = x;
#pragma unroll
            for (int o = 1; o < 64; o <<= 1) {
                int v = __shfl_up(x, (unsigned)o);
                if (lane >= o) x += v;
            }
            if (base + lane < ncells) s_pref[base + lane] = run + x - own;
            run += __shfl(x, 63);
        }
        if (lane == 0) s_pref[ncells] = run;
    }
    __syncthreads();

    int total = s_pref[ncells];
    const float4* pl = plist4 + ((size_t)b << 14);
    for (int ii = t; ii < total; ii += 512) {
        int lo = 0, hi = ncells;
        while (hi - lo > 1) {
            int mid = (lo + hi) >> 1;
            if (s_pref[mid] <= ii) lo = mid; else hi = mid;
        }
        float4 p = pl[s_cstart[lo] + (ii - s_pref[lo])];
        float dx = fabsf(p.x - cx);
        float dy = fabsf(p.y - cy);
        float dz = fabsf(p.z - cz);
        if (dx <= hx && dy <= hy && dz <= hz) {
            int pos = atomicAdd(&s_scnt, 1);
            if (pos < SELCAP_) s_sel[pos] = __float_as_int(p.w);
        }
    }
    __syncthreads();
    int scnt = min(s_scnt, SELCAP_);

    if (scnt > 0) {
        int count = min(scnt, NS_);
        if (scnt <= NS_) {
            // wave-0 shfl bitonic over 64 lanes: no block barriers
            if (wave == 0) {
                int v = (lane < scnt) ? s_sel[lane] : 0x7fffffff;
#pragma unroll
                for (int k = 2; k <= 64; k <<= 1) {
                    for (int j = k >> 1; j > 0; j >>= 1) {
                        int pv = __shfl_xor(v, (unsigned)j);
                        bool dir   = (lane & k) == 0;
                        bool lower = (lane & j) == 0;
                        int mn = min(v, pv), mx = max(v, pv);
                        v = dir ? (lower ? mn : mx) : (lower ? mx : mn);
                    }
                }
                s_idx[lane] = (lane < count) ? v : 0;
                if (lane == 0) s_count = count;
            }
        } else if (scnt <= 512) {
            // 8 per-wave sorts (0 barriers each) + rank-merge (2 barriers)
            int nw = (scnt + 63) >> 6;
            int base = wave << 6;
            int v = (base + lane < scnt) ? s_sel[base + lane] : 0x7fffffff;
#pragma unroll
            for (int k = 2; k <= 64; k <<= 1) {
                for (int j = k >> 1; j > 0; j >>= 1) {
                    int pv = __shfl_xor(v, (unsigned)j);
                    bool dir   = (lane & k) == 0;
                    bool lower = (lane & j) == 0;
                    int mn = min(v, pv), mx = max(v, pv);
                    v = dir ? (lower ? mn : mx) : (lower ? mx : mn);
                }
            }
            s_sel[base + lane] = v;       // sorted slice, distinct values
            __syncthreads();
            int e = s_sel[t];
            if (t < (nw << 6) && e != 0x7fffffff) {
                int r = lane;             // rank within own sorted slice
#pragma unroll
                for (int w = 0; w < 8; ++w) {
                    if (w == wave || w >= nw) continue;
                    int bw = w << 6;
                    int pos = 0;
#pragma unroll
                    for (int s2 = 32; s2 >= 1; s2 >>= 1)
                        if (s_sel[bw + pos + s2 - 1] < e) pos += s2;
                    if (s_sel[bw + pos] < e) ++pos;   // pos in [0,64]
                    r += pos;
                }
                if (r < NS_) s_idx[r] = e;   // ranks 0..count-1 fully cover
            }
            if (t == 0) s_count = NS_;        // count == 64 here
        } else {
            // block bitonic over m = next pow2 >= scnt (safety net)
            int m = NS_;
            while (m < scnt) m <<= 1;
            for (int ii = t; ii < m; ii += 512)
                if (ii >= scnt) s_sel[ii] = 0x7fffffff;
            __syncthreads();
            for (int k = 2; k <= m; k <<= 1) {
                for (int j = k >> 1; j > 0; j >>= 1) {
                    for (int ii = t; ii < m; ii += 512) {
                        int ixj = ii ^ j;
                        if (ixj > ii) {
                            int va = s_sel[ii], vb = s_sel[ixj];
                            bool up = ((ii & k) == 0);
                            if ((va > vb) == up) { s_sel[ii] = vb; s_sel[ixj] = va; }
                        }
                    }
                    __syncthreads();
                }
            }
            if (t < NS_) s_idx[t] = (t < count) ? s_sel[t] : 0;
            if (t == 0)  s_count = count;
        }
    } else {
        // radius fallback: ordered 8-segment scan (early exit ~9 iters at
        // ball density 0.11)
        const float R2 = (float)(0.3 * 0.3);
        const int seg = N_ / 8;           // 2048
        int n0s = wave * seg;
        unsigned long long ltm = (1ull << lane) - 1ull;
        int cnt = 0;
        for (int it = 0; it < seg / 64; ++it) {
            int n = n0s + it * 64 + lane;
            float dx = kb[3*n + 0] - cx;
            float dy = kb[3*n + 1] - cy;
            float dz = kb[3*n + 2] - cz;
            float d2 = dx*dx + dy*dy + dz*dz;   // contract off: matches numpy
            bool r = d2 <= R2;
            unsigned long long mm = __ballot(r);
            if (r) {
                int p = cnt + __popcll(mm & ltm);
                if (p < NS_) s_list[wave][p] = n;
            }
            cnt += __popcll(mm);
            if (cnt >= NS_) break;
        }
        if (lane == 0) s_cnt8[wave] = cnt;
        __syncthreads();
        if (wave == 0) {
            int tot = 0;
#pragma unroll
            for (int w = 0; w < 8; ++w) tot += s_cnt8[w];
            int count = min(tot, NS_);
            int j = lane;
            int idx = 0;
            if (j < count) {
                int w = 0, rem = j;
                while (rem >= s_cnt8[w]) { rem -= s_cnt8[w]; ++w; }
                idx = s_list[w][rem];
            }
            s_idx[j] = idx;
            if (lane == 0) s_count = count;
        }
    }
    __syncthreads();

    // epilogue: mask + centered xyz
    int count = s_count;
    if (t < NS_) {
        int j = t, idx = s_idx[j];
        out_mask[(size_t)bq * NS_ + j] = (j >= count && j > 0) ? 1.0f : 0.0f;
        float px = kb[3*idx + 0] - cx;
        float py = kb[3*idx + 1] - cy;
        float pz = kb[3*idx + 2] - cz;
        size_t xb = ((size_t)b * 3) * NQ_ * NS_ + (size_t)q * NS_ + j;
        out_xyz[xb]                       = px;
        out_xyz[xb +     (size_t)NQ_*NS_] = py;
        out_xyz[xb + 2 * (size_t)NQ_*NS_] = pz;
    }

    // gather: 2 chunks of 64 channels through a 64x65 tile
    const float4* ft4 = (const float4*)feat_t + (size_t)b * N_ * (C_ / 4);
    float* ob = out_feat + (size_t)b * C_ * NQ_ * NS_ + (size_t)q * NS_;
#pragma unroll
    for (int chunk = 0; chunk < 2; ++chunk) {
#pragma unroll
        for (int k = 0; k < 2; ++k) {
            int u  = t + k * 512;         // 0..1023
            int j  = u >> 4;              // row (slot)
            int c4 = u & 15;              // float4 within chunk
            float4 v = ft4[(size_t)s_idx[j] * (C_ / 4) + chunk * 16 + c4];
            tile[j][c4*4 + 0] = v.x;
            tile[j][c4*4 + 1] = v.y;
            tile[j][c4*4 + 2] = v.z;
            tile[j][c4*4 + 3] = v.w;
        }
        __syncthreads();
#pragma unroll
        for (int r = 0; r < 8; ++r) {
            int cl = wave + r * 8;        // chunk-local channel
            __builtin_nontemporal_store(tile[lane][cl],
                &ob[(size_t)(chunk * 64 + cl) * (NQ_ * NS_) + lane]);
        }
        __syncthreads();
    }
}

// ---------------------------------------------------------------------------
// Minimal-workspace fallback (linear select + direct gather).
// ---------------------------------------------------------------------------
__global__ __launch_bounds__(256) void select_lin_k(
    const float* __restrict__ key_xyz, const float* __restrict__ query,
    int* __restrict__ idx_out, float* __restrict__ out_xyz,
    float* __restrict__ out_mask)
{
    int bq = blockIdx.x;
    int b  = bq >> 10;
    int q  = bq & (NQ_ - 1);
    int t    = threadIdx.x;
    int wave = t >> 6;
    int lane = t & 63;

    __shared__ int s_list[4][NS_];
    __shared__ int s_cnt[4];

    const float* qp = query + (size_t)bq * 6;
    float cx = qp[0], cy = qp[1], cz = qp[2];
    float hx = 0.5f * qp[3], hy = 0.5f * qp[4], hz = 0.5f * qp[5];
    const float* kb = key_xyz + (size_t)b * N_ * 3;

    const int seg = N_ / 4;
    int n0 = wave * seg;
    unsigned long long lt = (1ull << lane) - 1ull;

    int cnt = 0;
    for (int it = 0; it < seg / 64; ++it) {
        int n = n0 + it * 64 + lane;
        float dx = fabsf(kb[3*n + 0] - cx);
        float dy = fabsf(kb[3*n + 1] - cy);
        float dz = fabsf(kb[3*n + 2] - cz);
        bool inside = (dx <= hx) && (dy <= hy) && (dz <= hz);
        unsigned long long m = __ballot(inside);
        if (inside) {
            int p = cnt + __popcll(m & lt);
            if (p < NS_) s_list[wave][p] = n;
        }
        cnt += __popcll(m);
        if (cnt >= NS_) break;
    }
    if (lane == 0) s_cnt[wave] = cnt;
    __syncthreads();

    int ti = s_cnt[0] + s_cnt[1] + s_cnt[2] + s_cnt[3];
    if (ti == 0) {
        const float R2 = (float)(0.3 * 0.3);
        cnt = 0;
        for (int it = 0; it < seg / 64; ++it) {
            int n = n0 + it * 64 + lane;
            float dx = kb[3*n + 0] - cx;
            float dy = kb[3*n + 1] - cy;
            float dz = kb[3*n + 2] - cz;
            float d2 = dx*dx + dy*dy + dz*dz;
            bool r = d2 <= R2;
            unsigned long long m = __ballot(r);
            if (r) {
                int p = cnt + __popcll(m & lt);
                if (p < NS_) s_list[wave][p] = n;
            }
            cnt += __popcll(m);
            if (cnt >= NS_) break;
        }
        if (lane == 0) s_cnt[wave] = cnt;
    }
    __syncthreads();

    if (wave == 0) {
        int c0s = min(s_cnt[0], NS_);
        int c1s = min(s_cnt[1], NS_);
        int c2s = min(s_cnt[2], NS_);
        int tot   = s_cnt[0] + s_cnt[1] + s_cnt[2] + s_cnt[3];
        int count = min(tot, NS_);
        int j = lane;
        int idx = 0;
        if (j < count) {
            int o1 = c0s, o2 = o1 + c1s, o3 = o2 + c2s;
            if      (j < o1) idx = s_list[0][j];
            else if (j < o2) idx = s_list[1][j - o1];
            else if (j < o3) idx = s_list[2][j - o2];
            else             idx = s_list[3][j - o3];
        }
        idx_out[(size_t)bq * NS_ + j] = idx;
        out_mask[(size_t)bq * NS_ + j] = (j >= count && j > 0) ? 1.0f : 0.0f;
        float px = kb[3*idx + 0] - cx;
        float py = kb[3*idx + 1] - cy;
        float pz = kb[3*idx + 2] - cz;
        size_t xb = ((size_t)b * 3) * NQ_ * NS_ + (size_t)q * NS_ + j;
        out_xyz[xb]                       = px;
        out_xyz[xb +     (size_t)NQ_*NS_] = py;
        out_xyz[xb + 2 * (size_t)NQ_*NS_] = pz;
    }
}

__global__ __launch_bounds__(256) void gather_direct_k(
    const int* __restrict__ idx_in, const float* __restrict__ key_feat,
    float* __restrict__ out_feat)
{
    int bq = blockIdx.x;
    int b  = bq >> 10;
    int q  = bq & (NQ_ - 1);
    int t    = threadIdx.x;
    int wave = t >> 6;
    int lane = t & 63;
    __shared__ int s_idx[NS_];
    if (t < NS_) s_idx[t] = idx_in[(size_t)bq * NS_ + t];
    __syncthreads();
    const float* fb = key_feat + (size_t)b * C_ * N_;
    float* ob = out_feat + (size_t)b * C_ * NQ_ * NS_ + (size_t)q * NS_;
    int idx = s_idx[lane];
    for (int c = wave; c < C_; c += 4)
        ob[(size_t)c * NQ_ * NS_ + lane] = fb[(size_t)c * N_ + idx];
}

extern "C" void kernel_launch(void* const* d_in, const int* in_sizes, int n_in,
                              void* d_out, int out_size, void* d_ws, size_t ws_size,
                              hipStream_t stream) {
    const float* key_xyz  = (const float*)d_in[0];
    const float* key_feat = (const float*)d_in[1];
    const float* query    = (const float*)d_in[2];

    float* out      = (float*)d_out;
    float* out_xyz  = out;
    float* out_feat = out + (size_t)B_ * 3 * NQ_ * NS_;
    float* out_mask = out_feat + (size_t)B_ * C_ * NQ_ * NS_;

    char* ws = (char*)d_ws;
    float*  ft      = (float*)(ws + OFF_FEAT);
    int*    counts  = (int*)(ws + OFF_COUNTS);
    int*    cursor  = (int*)(ws + OFF_CURSOR);
    int2*   cinfo   = (int2*)(ws + OFF_CINFO);
    float4* plist4  = (float4*)(ws + OFF_PLIST4);

    if (ws_size >= WS_NEED) {
        hipMemsetAsync(counts, 0, (size_t)B_ * NCELL_ * 4, stream);
        bin_count_k<<<dim3(B_ * N_ / 256), dim3(256), 0, stream>>>(key_xyz, counts);
        scan_k<<<dim3(B_), dim3(1024), 0, stream>>>(counts, cinfo, cursor);
        scatter_transpose_k<<<dim3(TBLK_ + B_ * N_ / 256), dim3(256), 0, stream>>>(
            key_xyz, key_feat, cursor, plist4, ft);
        selgather_k<<<dim3(B_ * NQ_), dim3(512), 0, stream>>>(
            key_xyz, query, cinfo, plist4, ft, out_xyz, out_feat, out_mask);
    } else {
        int* d_idx = (int*)d_ws;
        select_lin_k<<<dim3(B_ * NQ_), dim3(256), 0, stream>>>(
            key_xyz, query, d_idx, out_xyz, out_mask);
        gather_direct_k<<<dim3(B_ * NQ_), dim3(256), 0, stream>>>(
            d_idx, key_feat, out_feat);
    }
}

// Round 11
// 197.081 us; speedup vs baseline: 1.5415x; 1.0113x over previous
//
#include <hip/hip_runtime.h>

#pragma clang fp contract(off)

#define B_  4
#define N_  16384
#define NQ_ 1024
#define C_  128
#define NS_ 64
#define G_  16          // grid cells per dim
#define NCELL_ 4096     // G^3
#define MAXCELLS_ 224   // tight bounds: hx<=0.125 -> <=6 cells/dim -> <=216
#define SELCAP_ 1024    // inside-list capacity (max expected ~350)

// native vector type for nontemporal builtins (HIP float4 is a class type,
// which __builtin_nontemporal_* rejects)
typedef float vf4 __attribute__((ext_vector_type(4)));

// ---- workspace layout (bytes) ----
#define OFF_FEAT   ((size_t)0)
#define SZ_FEAT    ((size_t)B_*N_*C_*4)                 // 33.5 MB transposed features
#define OFF_COUNTS (OFF_FEAT + SZ_FEAT)
#define OFF_CURSOR (OFF_COUNTS + (size_t)B_*NCELL_*4)
#define OFF_CINFO  (OFF_CURSOR + (size_t)B_*NCELL_*4)   // int2 {count,start}
#define OFF_PLIST4 (OFF_CINFO + (size_t)B_*NCELL_*8)    // float4 {x,y,z,idx}
#define WS_NEED    (OFF_PLIST4 + (size_t)B_*N_*16)

__device__ __forceinline__ int cell_of(float x, float y, float z) {
    int ix = (int)(x * (float)G_); ix = min(G_ - 1, max(0, ix));
    int iy = (int)(y * (float)G_); iy = min(G_ - 1, max(0, iy));
    int iz = (int)(z * (float)G_); iz = min(G_ - 1, max(0, iz));
    return ix + (iy << 4) + (iz << 8);
}

// epsilon-safe cell range for interval [c-h, c+h]: x*16 is EXACT (pow2 mul);
// inside test |fl(x-c)|<=h and lo/hi=fl(c-+h) carry <=2 roundings =>
// 3e-7 relative (+1e-9 abs) strictly covers them.
__device__ __forceinline__ int cell_lo(float c, float h) {
    float lo = c - h;
    lo -= fabsf(lo) * 3e-7f + 1e-9f;
    return max(0, (int)floorf(lo * (float)G_));
}
__device__ __forceinline__ int cell_hi(float c, float h) {
    float hi = c + h;
    hi += fabsf(hi) * 3e-7f + 1e-9f;
    return min(G_ - 1, (int)floorf(hi * (float)G_));
}

__global__ __launch_bounds__(256) void bin_count_k(const float* __restrict__ key_xyz,
                                                   int* __restrict__ counts) {
    int id = blockIdx.x * 256 + threadIdx.x;   // < B*N
    int b = id >> 14, n = id & (N_ - 1);
    const float* p = key_xyz + ((size_t)b * N_ + n) * 3;
    int cid = cell_of(p[0], p[1], p[2]);
    atomicAdd(&counts[(b << 12) + cid], 1);
}

// wave-shfl scan: 2 barriers
__global__ __launch_bounds__(1024) void scan_k(const int* __restrict__ counts,
                                               int2* __restrict__ cinfo,
                                               int* __restrict__ cursor) {
    __shared__ int wsum[16];
    int b = blockIdx.x, t = threadIdx.x;
    int wave = t >> 6, lane = t & 63;
    int base = b << 12;
    int c0 = t << 2;
    int v0 = counts[base + c0 + 0], v1 = counts[base + c0 + 1];
    int v2 = counts[base + c0 + 2], v3 = counts[base + c0 + 3];
    int s = v0 + v1 + v2 + v3;
    int x = s;
#pragma unroll
    for (int o = 1; o < 64; o <<= 1) {
        int v = __shfl_up(x, (unsigned)o);
        if (lane >= o) x += v;
    }
    if (lane == 63) wsum[wave] = x;
    __syncthreads();
    if (t < 16) {
        int y = wsum[t];
#pragma unroll
        for (int o = 1; o < 16; o <<= 1) {
            int v = __shfl_up(y, (unsigned)o);
            if (t >= o) y += v;
        }
        wsum[t] = y;
    }
    __syncthreads();
    int off = (wave ? wsum[wave - 1] : 0) + x - s;   // exclusive prefix
    int e0 = off, e1 = e0 + v0, e2 = e1 + v1, e3 = e2 + v2;
    cinfo[base + c0 + 0] = make_int2(v0, e0); cursor[base + c0 + 0] = e0;
    cinfo[base + c0 + 1] = make_int2(v1, e1); cursor[base + c0 + 1] = e1;
    cinfo[base + c0 + 2] = make_int2(v2, e2); cursor[base + c0 + 2] = e2;
    cinfo[base + c0 + 3] = make_int2(v3, e3); cursor[base + c0 + 3] = e3;
}

// ---------------------------------------------------------------------------
// Fused: blocks [0,256) scatter points into plist4 {x,y,z,bitcast(idx)};
// blocks [256, 256+2048) transpose key_features [B][C][N] -> [B][N][C] using
// 64x64 tiles with float4 global loads/stores (4x fewer VMEM instructions).
// ---------------------------------------------------------------------------
#define TTBLK_ (B_ * (C_/64) * (N_/64))   // 2048
__global__ __launch_bounds__(256) void scatter_transpose_k(
    const float* __restrict__ key_xyz, const float* __restrict__ key_feat,
    int* __restrict__ cursor, float4* __restrict__ plist4,
    float* __restrict__ feat_t)
{
    __shared__ float ttile[64][65];   // scalar LDS, 2-way conflicts both sides
    int t = threadIdx.x;
    if (blockIdx.x < 256) {
        int id = blockIdx.x * 256 + t;   // < B*N
        int b = id >> 14, n = id & (N_ - 1);
        const float* p = key_xyz + ((size_t)b * N_ + n) * 3;
        float x = p[0], y = p[1], z = p[2];
        int cid = cell_of(x, y, z);
        int pos = atomicAdd(&cursor[(b << 12) + cid], 1);   // batch-local absolute
        plist4[(b << 14) + pos] = make_float4(x, y, z, __int_as_float(n));
        return;
    }
    int id2 = blockIdx.x - 256;        // < 2048
    int b   = id2 >> 9;
    int rem = id2 & 511;
    int cb  = rem >> 8;                // 0..1  (64-channel block)
    int nb  = rem & 255;               // 0..255 (64-point block)
    {
        int nf = t & 15, cr = t >> 4;  // nf: float4 along n, cr: channel row
#pragma unroll
        for (int k = 0; k < 4; ++k) {
            int c = cr + 16 * k;
            vf4 v = __builtin_nontemporal_load(
                (const vf4*)&key_feat[((size_t)(b * C_ + cb * 64 + c)) * N_ + nb * 64 + 4 * nf]);
            ttile[c][4*nf + 0] = v.x; ttile[c][4*nf + 1] = v.y;
            ttile[c][4*nf + 2] = v.z; ttile[c][4*nf + 3] = v.w;
        }
    }
    __syncthreads();
    {
        int cf = t & 15, nr = t >> 4;  // cf: float4 along c, nr: point row
#pragma unroll
        for (int k = 0; k < 4; ++k) {
            int n = nr + 16 * k;
            vf4 w;
            w.x = ttile[4*cf + 0][n];
            w.y = ttile[4*cf + 1][n];
            w.z = ttile[4*cf + 2][n];
            w.w = ttile[4*cf + 3][n];
            *(vf4*)&feat_t[((size_t)b * N_ + nb * 64 + n) * C_ + cb * 64 + 4 * cf] = w;
        }
    }
}

// ---------------------------------------------------------------------------
// Fused select + gather: one 512-thread block per (b,q), XCD-swizzled.
// LDS union: select arrays (dead after s_idx) overlaid with the full 64x128
// gather tile -> single-phase gather (1 barrier), upfront float4 loads
// (latency hidden under xyz epilogue), float4 nontemporal stores.
// ---------------------------------------------------------------------------
__global__ __launch_bounds__(512) void selgather_k(
    const float* __restrict__ key_xyz, const float* __restrict__ query,
    const int2* __restrict__ cinfo, const float4* __restrict__ plist4,
    const float* __restrict__ feat_t,
    float* __restrict__ out_xyz, float* __restrict__ out_feat,
    float* __restrict__ out_mask)
{
    union SMem {
        struct {
            int ccnt[MAXCELLS_];
            int cstart[MAXCELLS_];
            int pref[MAXCELLS_ + 1];
            int sel[SELCAP_];
            int list[8][NS_];          // radius fallback
        } s;
        float tile[NS_][132];          // 33 KB; stride 132: 16B-aligned rows
    };
    __shared__ __align__(16) SMem u;
    __shared__ int s_scnt, s_count, s_cnt8[8], s_idx[NS_];

    // XCD-aware swizzle: block i -> XCD i&7 -> batch (i&7)>>1
    int i    = blockIdx.x;
    int xcd  = i & 7;
    int b    = xcd >> 1;
    int q    = ((i >> 3) << 1) | (xcd & 1);
    int bq   = (b << 10) | q;
    int t    = threadIdx.x;
    int wave = t >> 6, lane = t & 63;

    const float* qp = query + (size_t)bq * 6;
    float cx = qp[0], cy = qp[1], cz = qp[2];
    float hx = 0.5f * qp[3], hy = 0.5f * qp[4], hz = 0.5f * qp[5];
    const float* kb = key_xyz + (size_t)b * N_ * 3;

    if (t == 0) s_scnt = 0;

    // tight epsilon-safe cell window (no +-1 expansion)
    int ilox = cell_lo(cx, hx), ihix = cell_hi(cx, hx);
    int iloy = cell_lo(cy, hy), ihiy = cell_hi(cy, hy);
    int iloz = cell_lo(cz, hz), ihiz = cell_hi(cz, hz);
    int nx = ihix - ilox + 1, ny = ihiy - iloy + 1, nz = ihiz - iloz + 1;
    int ncells = nx * ny * nz;            // <= 216

    const int2* ci = cinfo + (b << 12);
    for (int cc = t; cc < ncells; cc += 512) {
        int iz = cc / (nx * ny);
        int r  = cc - iz * (nx * ny);
        int iy = r / nx;
        int ix = r - iy * nx;
        int cid = (ilox + ix) + ((iloy + iy) << 4) + ((iloz + iz) << 8);
        int2 v = ci[cid];
        u.s.ccnt[cc]   = v.x;
        u.s.cstart[cc] = v.y;
    }
    __syncthreads();

    if (wave == 0) {                      // exclusive prefix over <=216 counts
        int run = 0;
        for (int base = 0; base < ncells; base += 64) {
            int x = (base + lane < ncells) ? u.s.ccnt[base + lane] : 0;
            int own = x;
#pragma unroll
            for (int o = 1; o < 64; o <<= 1) {
                int v = __shfl_up(x, (unsigned)o);
                if (lane >= o) x += v;
            }
            if (base + lane < ncells) u.s.pref[base + lane] = run + x - own;
            run += __shfl(x, 63);
        }
        if (lane == 0) u.s.pref[ncells] = run;
    }
    __syncthreads();

    int total = u.s.pref[ncells];
    const float4* pl = plist4 + ((size_t)b << 14);
    for (int ii = t; ii < total; ii += 512) {
        int lo = 0, hi = ncells;
        while (hi - lo > 1) {
            int mid = (lo + hi) >> 1;
            if (u.s.pref[mid] <= ii) lo = mid; else hi = mid;
        }
        float4 p = pl[u.s.cstart[lo] + (ii - u.s.pref[lo])];
        float dx = fabsf(p.x - cx);
        float dy = fabsf(p.y - cy);
        float dz = fabsf(p.z - cz);
        if (dx <= hx && dy <= hy && dz <= hz) {
            int pos = atomicAdd(&s_scnt, 1);
            if (pos < SELCAP_) u.s.sel[pos] = __float_as_int(p.w);
        }
    }
    __syncthreads();
    int scnt = min(s_scnt, SELCAP_);

    if (scnt > 0) {
        int count = min(scnt, NS_);
        if (scnt <= NS_) {
            // wave-0 shfl bitonic over 64 lanes: no block barriers
            if (wave == 0) {
                int v = (lane < scnt) ? u.s.sel[lane] : 0x7fffffff;
#pragma unroll
                for (int k = 2; k <= 64; k <<= 1) {
                    for (int j = k >> 1; j > 0; j >>= 1) {
                        int pv = __shfl_xor(v, (unsigned)j);
                        bool dir   = (lane & k) == 0;
                        bool lower = (lane & j) == 0;
                        int mn = min(v, pv), mx = max(v, pv);
                        v = dir ? (lower ? mn : mx) : (lower ? mx : mn);
                    }
                }
                s_idx[lane] = (lane < count) ? v : 0;
                if (lane == 0) s_count = count;
            }
        } else if (scnt <= 512) {
            // 8 per-wave sorts (0 barriers each) + rank-merge (2 barriers)
            int nw = (scnt + 63) >> 6;
            int base = wave << 6;
            int v = (base + lane < scnt) ? u.s.sel[base + lane] : 0x7fffffff;
#pragma unroll
            for (int k = 2; k <= 64; k <<= 1) {
                for (int j = k >> 1; j > 0; j >>= 1) {
                    int pv = __shfl_xor(v, (unsigned)j);
                    bool dir   = (lane & k) == 0;
                    bool lower = (lane & j) == 0;
                    int mn = min(v, pv), mx = max(v, pv);
                    v = dir ? (lower ? mn : mx) : (lower ? mx : mn);
                }
            }
            u.s.sel[base + lane] = v;       // sorted slice, distinct values
            __syncthreads();
            int e = u.s.sel[t];
            if (t < (nw << 6) && e != 0x7fffffff) {
                int r = lane;               // rank within own sorted slice
#pragma unroll
                for (int w = 0; w < 8; ++w) {
                    if (w == wave || w >= nw) continue;
                    int bw = w << 6;
                    int pos = 0;
#pragma unroll
                    for (int s2 = 32; s2 >= 1; s2 >>= 1)
                        if (u.s.sel[bw + pos + s2 - 1] < e) pos += s2;
                    if (u.s.sel[bw + pos] < e) ++pos;   // pos in [0,64]
                    r += pos;
                }
                if (r < NS_) s_idx[r] = e;  // ranks 0..count-1 fully cover
            }
            if (t == 0) s_count = NS_;      // count == 64 here
        } else {
            // block bitonic over m = next pow2 >= scnt (safety net)
            int m = NS_;
            while (m < scnt) m <<= 1;
            for (int ii = t; ii < m; ii += 512)
                if (ii >= scnt) u.s.sel[ii] = 0x7fffffff;
            __syncthreads();
            for (int k = 2; k <= m; k <<= 1) {
                for (int j = k >> 1; j > 0; j >>= 1) {
                    for (int ii = t; ii < m; ii += 512) {
                        int ixj = ii ^ j;
                        if (ixj > ii) {
                            int va = u.s.sel[ii], vb = u.s.sel[ixj];
                            bool up = ((ii & k) == 0);
                            if ((va > vb) == up) { u.s.sel[ii] = vb; u.s.sel[ixj] = va; }
                        }
                    }
                    __syncthreads();
                }
            }
            if (t < NS_) s_idx[t] = (t < count) ? u.s.sel[t] : 0;
            if (t == 0)  s_count = count;
        }
    } else {
        // radius fallback: ordered 8-segment scan (round-2 semantics)
        const float R2 = (float)(0.3 * 0.3);
        const int seg = N_ / 8;           // 2048
        int n0s = wave * seg;
        unsigned long long ltm = (1ull << lane) - 1ull;
        int cnt = 0;
        for (int it = 0; it < seg / 64; ++it) {
            int n = n0s + it * 64 + lane;
            float dx = kb[3*n + 0] - cx;
            float dy = kb[3*n + 1] - cy;
            float dz = kb[3*n + 2] - cz;
            float d2 = dx*dx + dy*dy + dz*dz;   // contract off: matches numpy
            bool r = d2 <= R2;
            unsigned long long mm = __ballot(r);
            if (r) {
                int p = cnt + __popcll(mm & ltm);
                if (p < NS_) u.s.list[wave][p] = n;
            }
            cnt += __popcll(mm);
            if (cnt >= NS_) break;
        }
        if (lane == 0) s_cnt8[wave] = cnt;
        __syncthreads();
        if (wave == 0) {
            int tot = 0;
#pragma unroll
            for (int w = 0; w < 8; ++w) tot += s_cnt8[w];
            int count = min(tot, NS_);
            int j = lane;
            int idx = 0;
            if (j < count) {
                int w = 0, rem = j;
                while (rem >= s_cnt8[w]) { rem -= s_cnt8[w]; ++w; }
                idx = u.s.list[w][rem];
            }
            s_idx[j] = idx;
            if (lane == 0) s_count = count;
        }
    }
    __syncthreads();   // s_idx/s_count final; select smem dead -> tile may reuse

    // ---- gather: all loads upfront (hidden under epilogue), one LDS pass ----
    const float4* ft4 = (const float4*)feat_t + (size_t)b * N_ * (C_ / 4);
    int c4 = t & 31;                       // float4 index within row
    int j0 = t >> 5;                       // 0..15
    int r0 = s_idx[j0], r1 = s_idx[j0 + 16], r2 = s_idx[j0 + 32], r3 = s_idx[j0 + 48];
    float4 v0 = ft4[(size_t)r0 * (C_/4) + c4];
    float4 v1 = ft4[(size_t)r1 * (C_/4) + c4];
    float4 v2 = ft4[(size_t)r2 * (C_/4) + c4];
    float4 v3 = ft4[(size_t)r3 * (C_/4) + c4];

    // epilogue (overlaps load latency): mask + centered xyz
    int count = s_count;
    if (t < NS_) {
        int j = t, idx = s_idx[j];
        out_mask[(size_t)bq * NS_ + j] = (j >= count && j > 0) ? 1.0f : 0.0f;
        float px = kb[3*idx + 0] - cx;
        float py = kb[3*idx + 1] - cy;
        float pz = kb[3*idx + 2] - cz;
        size_t xb = ((size_t)b * 3) * NQ_ * NS_ + (size_t)q * NS_ + j;
        out_xyz[xb]                       = px;
        out_xyz[xb +     (size_t)NQ_*NS_] = py;
        out_xyz[xb + 2 * (size_t)NQ_*NS_] = pz;
    }

    // swizzled b128 LDS writes: physical col4 = c4 ^ ((j>>2)&7)
    *(float4*)&u.tile[j0     ][4 * (c4 ^ (((j0     ) >> 2) & 7))] = v0;
    *(float4*)&u.tile[j0 + 16][4 * (c4 ^ (((j0 + 16) >> 2) & 7))] = v1;
    *(float4*)&u.tile[j0 + 32][4 * (c4 ^ (((j0 + 32) >> 2) & 7))] = v2;
    *(float4*)&u.tile[j0 + 48][4 * (c4 ^ (((j0 + 48) >> 2) & 7))] = v3;
    __syncthreads();

    // float4 stores: 16 lanes x 16B = 256B contiguous per channel row
    float* ob = out_feat + (size_t)b * C_ * NQ_ * NS_ + (size_t)q * NS_;
    int jg = t & 15, cb0 = t >> 4;         // cb0: 0..31
#pragma unroll
    for (int k = 0; k < 4; ++k) {
        int cc = cb0 + 32 * k;
        int ch = cc >> 2, cl = cc & 3;
        int key = jg & 7;                  // (4*jg+kk)>>2 & 7 == jg&7 for kk<4
        vf4 w;
        w.x = u.tile[4*jg + 0][4 * (ch ^ key) + cl];
        w.y = u.tile[4*jg + 1][4 * (ch ^ key) + cl];
        w.z = u.tile[4*jg + 2][4 * (ch ^ key) + cl];
        w.w = u.tile[4*jg + 3][4 * (ch ^ key) + cl];
        __builtin_nontemporal_store(w, (vf4*)&ob[(size_t)cc * (NQ_ * NS_) + 4 * jg]);
    }
}

// ---------------------------------------------------------------------------
// Minimal-workspace fallback (linear select + direct gather).
// ---------------------------------------------------------------------------
__global__ __launch_bounds__(256) void select_lin_k(
    const float* __restrict__ key_xyz, const float* __restrict__ query,
    int* __restrict__ idx_out, float* __restrict__ out_xyz,
    float* __restrict__ out_mask)
{
    int bq = blockIdx.x;
    int b  = bq >> 10;
    int q  = bq & (NQ_ - 1);
    int t    = threadIdx.x;
    int wave = t >> 6;
    int lane = t & 63;

    __shared__ int s_list[4][NS_];
    __shared__ int s_cnt[4];

    const float* qp = query + (size_t)bq * 6;
    float cx = qp[0], cy = qp[1], cz = qp[2];
    float hx = 0.5f * qp[3], hy = 0.5f * qp[4], hz = 0.5f * qp[5];
    const float* kb = key_xyz + (size_t)b * N_ * 3;

    const int seg = N_ / 4;
    int n0 = wave * seg;
    unsigned long long lt = (1ull << lane) - 1ull;

    int cnt = 0;
    for (int it = 0; it < seg / 64; ++it) {
        int n = n0 + it * 64 + lane;
        float dx = fabsf(kb[3*n + 0] - cx);
        float dy = fabsf(kb[3*n + 1] - cy);
        float dz = fabsf(kb[3*n + 2] - cz);
        bool inside = (dx <= hx) && (dy <= hy) && (dz <= hz);
        unsigned long long m = __ballot(inside);
        if (inside) {
            int p = cnt + __popcll(m & lt);
            if (p < NS_) s_list[wave][p] = n;
        }
        cnt += __popcll(m);
        if (cnt >= NS_) break;
    }
    if (lane == 0) s_cnt[wave] = cnt;
    __syncthreads();

    int ti = s_cnt[0] + s_cnt[1] + s_cnt[2] + s_cnt[3];
    if (ti == 0) {
        const float R2 = (float)(0.3 * 0.3);
        cnt = 0;
        for (int it = 0; it < seg / 64; ++it) {
            int n = n0 + it * 64 + lane;
            float dx = kb[3*n + 0] - cx;
            float dy = kb[3*n + 1] - cy;
            float dz = kb[3*n + 2] - cz;
            float d2 = dx*dx + dy*dy + dz*dz;
            bool r = d2 <= R2;
            unsigned long long m = __ballot(r);
            if (r) {
                int p = cnt + __popcll(m & lt);
                if (p < NS_) s_list[wave][p] = n;
            }
            cnt += __popcll(m);
            if (cnt >= NS_) break;
        }
        if (lane == 0) s_cnt[wave] = cnt;
    }
    __syncthreads();

    if (wave == 0) {
        int c0s = min(s_cnt[0], NS_);
        int c1s = min(s_cnt[1], NS_);
        int c2s = min(s_cnt[2], NS_);
        int tot   = s_cnt[0] + s_cnt[1] + s_cnt[2] + s_cnt[3];
        int count = min(tot, NS_);
        int j = lane;
        int idx = 0;
        if (j < count) {
            int o1 = c0s, o2 = o1 + c1s, o3 = o2 + c2s;
            if      (j < o1) idx = s_list[0][j];
            else if (j < o2) idx = s_list[1][j - o1];
            else if (j < o3) idx = s_list[2][j - o2];
            else             idx = s_list[3][j - o3];
        }
        idx_out[(size_t)bq * NS_ + j] = idx;
        out_mask[(size_t)bq * NS_ + j] = (j >= count && j > 0) ? 1.0f : 0.0f;
        float px = kb[3*idx + 0] - cx;
        float py = kb[3*idx + 1] - cy;
        float pz = kb[3*idx + 2] - cz;
        size_t xb = ((size_t)b * 3) * NQ_ * NS_ + (size_t)q * NS_ + j;
        out_xyz[xb]                       = px;
        out_xyz[xb +     (size_t)NQ_*NS_] = py;
        out_xyz[xb + 2 * (size_t)NQ_*NS_] = pz;
    }
}

__global__ __launch_bounds__(256) void gather_direct_k(
    const int* __restrict__ idx_in, const float* __restrict__ key_feat,
    float* __restrict__ out_feat)
{
    int bq = blockIdx.x;
    int b  = bq >> 10;
    int q  = bq & (NQ_ - 1);
    int t    = threadIdx.x;
    int wave = t >> 6;
    int lane = t & 63;
    __shared__ int s_idx[NS_];
    if (t < NS_) s_idx[t] = idx_in[(size_t)bq * NS_ + t];
    __syncthreads();
    const float* fb = key_feat + (size_t)b * C_ * N_;
    float* ob = out_feat + (size_t)b * C_ * NQ_ * NS_ + (size_t)q * NS_;
    int idx = s_idx[lane];
    for (int c = wave; c < C_; c += 4)
        ob[(size_t)c * NQ_ * NS_ + lane] = fb[(size_t)c * N_ + idx];
}

extern "C" void kernel_launch(void* const* d_in, const int* in_sizes, int n_in,
                              void* d_out, int out_size, void* d_ws, size_t ws_size,
                              hipStream_t stream) {
    const float* key_xyz  = (const float*)d_in[0];
    const float* key_feat = (const float*)d_in[1];
    const float* query    = (const float*)d_in[2];

    float* out      = (float*)d_out;
    float* out_xyz  = out;
    float* out_feat = out + (size_t)B_ * 3 * NQ_ * NS_;
    float* out_mask = out_feat + (size_t)B_ * C_ * NQ_ * NS_;

    char* ws = (char*)d_ws;
    float*  ft      = (float*)(ws + OFF_FEAT);
    int*    counts  = (int*)(ws + OFF_COUNTS);
    int*    cursor  = (int*)(ws + OFF_CURSOR);
    int2*   cinfo   = (int2*)(ws + OFF_CINFO);
    float4* plist4  = (float4*)(ws + OFF_PLIST4);

    if (ws_size >= WS_NEED) {
        (void)hipMemsetAsync(counts, 0, (size_t)B_ * NCELL_ * 4, stream);
        bin_count_k<<<dim3(B_ * N_ / 256), dim3(256), 0, stream>>>(key_xyz, counts);
        scan_k<<<dim3(B_), dim3(1024), 0, stream>>>(counts, cinfo, cursor);
        scatter_transpose_k<<<dim3(256 + TTBLK_), dim3(256), 0, stream>>>(
            key_xyz, key_feat, cursor, plist4, ft);
        selgather_k<<<dim3(B_ * NQ_), dim3(512), 0, stream>>>(
            key_xyz, query, cinfo, plist4, ft, out_xyz, out_feat, out_mask);
    } else {
        int* d_idx = (int*)d_ws;
        select_lin_k<<<dim3(B_ * NQ_), dim3(256), 0, stream>>>(
            key_xyz, query, d_idx, out_xyz, out_mask);
        gather_direct_k<<<dim3(B_ * NQ_), dim3(256), 0, stream>>>(
            d_idx, key_feat, out_feat);
    }
}